// Round 1
// baseline (2781.556 us; speedup 1.0000x reference)
//
#include <hip/hip_runtime.h>

#define N_NODES 100000
#define N_EDGES 3200000

// ---------------------------------------------------------------------------
// Detect whether edge_index is stored as int64 (odd 32-bit words all zero for
// nonnegative indices < 2^31) or int32. One wave samples 512 positions.
// ---------------------------------------------------------------------------
__global__ void detect_i64_kernel(const unsigned int* __restrict__ ei,
                                  unsigned int* __restrict__ flag) {
    unsigned int v = 0;
    int lane = threadIdx.x;  // 64 threads
    for (int j = lane; j < 512; j += 64) v |= ei[2 * j + 1];
    unsigned long long any_nonzero = __ballot(v != 0u);
    if (lane == 0) *flag = (any_nonzero == 0ULL) ? 1u : 0u;
}

// ---------------------------------------------------------------------------
// h[i][c] = sum_k x[i][k] * W1[c][k]   (W1 row-major [16][58])
// ---------------------------------------------------------------------------
__global__ void linear1_kernel(const float* __restrict__ x,
                               const float* __restrict__ W1,
                               float* __restrict__ h, int n) {
    __shared__ float w[16 * 58];
    for (int idx = threadIdx.x; idx < 16 * 58; idx += blockDim.x)
        w[idx] = W1[idx];
    __syncthreads();

    int i = blockIdx.x * blockDim.x + threadIdx.x;
    if (i >= n) return;

    float xv[58];
    const float* xr = x + (long)i * 58;
#pragma unroll
    for (int k = 0; k < 58; ++k) xv[k] = xr[k];

    float4 o[4];
#pragma unroll
    for (int q = 0; q < 4; ++q) {
        float a[4];
#pragma unroll
        for (int r = 0; r < 4; ++r) {
            int c = q * 4 + r;
            float acc = 0.0f;
#pragma unroll
            for (int k = 0; k < 58; ++k) acc += xv[k] * w[c * 58 + k];
            a[r] = acc;
        }
        o[q] = make_float4(a[0], a[1], a[2], a[3]);
    }
    float4* hr = (float4*)(h + (long)i * 16);
    hr[0] = o[0]; hr[1] = o[1]; hr[2] = o[2]; hr[3] = o[3];
}

// ---------------------------------------------------------------------------
// For each edge (src -> dst): summed[dst][:] += h[src][:], cnt[dst] += 1
// ---------------------------------------------------------------------------
__global__ void scatter_kernel(const int* __restrict__ ei32,
                               const long long* __restrict__ ei64,
                               const unsigned int* __restrict__ flag,
                               const float* __restrict__ h,
                               float* __restrict__ summed,
                               float* __restrict__ cnt) {
    long e = (long)blockIdx.x * blockDim.x + threadIdx.x;
    if (e >= N_EDGES) return;

    long src, dst;
    if (*flag) {
        src = (long)ei64[e];
        dst = (long)ei64[N_EDGES + e];
    } else {
        src = (long)ei32[e];
        dst = (long)ei32[N_EDGES + e];
    }

    const float4* hs = (const float4*)(h + src * 16);
    float4 a = hs[0], b = hs[1], c = hs[2], d = hs[3];

    float* o = summed + dst * 16;
    atomicAdd(o + 0,  a.x); atomicAdd(o + 1,  a.y);
    atomicAdd(o + 2,  a.z); atomicAdd(o + 3,  a.w);
    atomicAdd(o + 4,  b.x); atomicAdd(o + 5,  b.y);
    atomicAdd(o + 6,  b.z); atomicAdd(o + 7,  b.w);
    atomicAdd(o + 8,  c.x); atomicAdd(o + 9,  c.y);
    atomicAdd(o + 10, c.z); atomicAdd(o + 11, c.w);
    atomicAdd(o + 12, d.x); atomicAdd(o + 13, d.y);
    atomicAdd(o + 14, d.z); atomicAdd(o + 15, d.w);
    atomicAdd(cnt + dst, 1.0f);
}

// ---------------------------------------------------------------------------
// out[i] = b2 + sum_c W2[c] * relu(summed[i][c]/max(cnt[i],1) + b1[c])
// ---------------------------------------------------------------------------
__global__ void finalize_kernel(const float* __restrict__ summed,
                                const float* __restrict__ cnt,
                                const float* __restrict__ b1,
                                const float* __restrict__ W2,
                                const float* __restrict__ b2,
                                float* __restrict__ out, int n) {
    int i = blockIdx.x * blockDim.x + threadIdx.x;
    if (i >= n) return;

    const float4* s = (const float4*)(summed + (long)i * 16);
    float4 s0 = s[0], s1 = s[1], s2 = s[2], s3 = s[3];
    float sv[16] = {s0.x, s0.y, s0.z, s0.w, s1.x, s1.y, s1.z, s1.w,
                    s2.x, s2.y, s2.z, s2.w, s3.x, s3.y, s3.z, s3.w};

    float inv = 1.0f / fmaxf(cnt[i], 1.0f);
    float acc = b2[0];
#pragma unroll
    for (int c = 0; c < 16; ++c)
        acc += W2[c] * fmaxf(sv[c] * inv + b1[c], 0.0f);
    out[i] = acc;
}

extern "C" void kernel_launch(void* const* d_in, const int* in_sizes, int n_in,
                              void* d_out, int out_size, void* d_ws, size_t ws_size,
                              hipStream_t stream) {
    const float* x  = (const float*)d_in[0];
    const void*  ei = d_in[1];
    const float* W1 = (const float*)d_in[2];
    const float* b1 = (const float*)d_in[3];
    const float* W2 = (const float*)d_in[4];
    const float* b2 = (const float*)d_in[5];
    float* out = (float*)d_out;

    float* ws     = (float*)d_ws;
    float* h      = ws;                  // N_NODES * 16
    float* summed = ws + N_NODES * 16;   // N_NODES * 16
    float* cnt    = ws + N_NODES * 32;   // N_NODES
    unsigned int* flag = (unsigned int*)(ws + N_NODES * 33);

    // Zero accumulators (summed + cnt are contiguous). Capture-safe.
    hipMemsetAsync(summed, 0, (size_t)(N_NODES * 17) * sizeof(float), stream);

    detect_i64_kernel<<<1, 64, 0, stream>>>((const unsigned int*)ei, flag);

    linear1_kernel<<<(N_NODES + 127) / 128, 128, 0, stream>>>(x, W1, h, N_NODES);

    scatter_kernel<<<(N_EDGES + 255) / 256, 256, 0, stream>>>(
        (const int*)ei, (const long long*)ei, flag, h, summed, cnt);

    finalize_kernel<<<(N_NODES + 255) / 256, 256, 0, stream>>>(
        summed, cnt, b1, W2, b2, out, N_NODES);
}

// Round 2
// 554.179 us; speedup vs baseline: 5.0192x; 5.0192x over previous
//
#include <hip/hip_runtime.h>

#define N_NODES 100000
#define N_EDGES 3200000
#define SCAN_BLOCK 512
#define NB_SCAN ((N_NODES + SCAN_BLOCK - 1) / SCAN_BLOCK)

// ---------------------------------------------------------------------------
// Detect int64 vs int32 edge_index (odd 32-bit words all zero => int64).
// ---------------------------------------------------------------------------
__global__ void detect_i64_kernel(const unsigned int* __restrict__ ei,
                                  unsigned int* __restrict__ flag) {
    unsigned int v = 0;
    int lane = threadIdx.x;  // 64 threads
    for (int j = lane; j < 512; j += 64) v |= ei[2 * j + 1];
    unsigned long long any_nonzero = __ballot(v != 0u);
    if (lane == 0) *flag = (any_nonzero == 0ULL) ? 1u : 0u;
}

// ---------------------------------------------------------------------------
// h[i][c] = sum_k x[i][k] * W1[c][k]
// ---------------------------------------------------------------------------
__global__ void linear1_kernel(const float* __restrict__ x,
                               const float* __restrict__ W1,
                               float* __restrict__ h, int n) {
    __shared__ float w[16 * 58];
    for (int idx = threadIdx.x; idx < 16 * 58; idx += blockDim.x)
        w[idx] = W1[idx];
    __syncthreads();

    int i = blockIdx.x * blockDim.x + threadIdx.x;
    if (i >= n) return;

    float xv[58];
    const float* xr = x + (long)i * 58;
#pragma unroll
    for (int k = 0; k < 58; ++k) xv[k] = xr[k];

    float4 o[4];
#pragma unroll
    for (int q = 0; q < 4; ++q) {
        float a[4];
#pragma unroll
        for (int r = 0; r < 4; ++r) {
            int c = q * 4 + r;
            float acc = 0.0f;
#pragma unroll
            for (int k = 0; k < 58; ++k) acc += xv[k] * w[c * 58 + k];
            a[r] = acc;
        }
        o[q] = make_float4(a[0], a[1], a[2], a[3]);
    }
    float4* hr = (float4*)(h + (long)i * 16);
    hr[0] = o[0]; hr[1] = o[1]; hr[2] = o[2]; hr[3] = o[3];
}

// ---------------------------------------------------------------------------
// CSR build phase 1: deg[dst]++
// ---------------------------------------------------------------------------
__global__ void count_kernel(const int* __restrict__ ei32,
                             const long long* __restrict__ ei64,
                             const unsigned int* __restrict__ flag,
                             int* __restrict__ deg) {
    long e = (long)blockIdx.x * blockDim.x + threadIdx.x;
    if (e >= N_EDGES) return;
    int dst = (*flag) ? (int)ei64[N_EDGES + e] : ei32[N_EDGES + e];
    atomicAdd(&deg[dst], 1);
}

// ---------------------------------------------------------------------------
// Scan: block-local exclusive scan of deg into cursor, block sums out.
// ---------------------------------------------------------------------------
__global__ void scan1_kernel(const int* __restrict__ deg,
                             int* __restrict__ cursor,
                             int* __restrict__ bsums, int n) {
    __shared__ int tmp[SCAN_BLOCK];
    int i = blockIdx.x * SCAN_BLOCK + threadIdx.x;
    int v = (i < n) ? deg[i] : 0;
    tmp[threadIdx.x] = v;
    __syncthreads();
#pragma unroll
    for (int d = 1; d < SCAN_BLOCK; d <<= 1) {
        int t = (threadIdx.x >= d) ? tmp[threadIdx.x - d] : 0;
        __syncthreads();
        tmp[threadIdx.x] += t;
        __syncthreads();
    }
    if (i < n) cursor[i] = tmp[threadIdx.x] - v;  // exclusive
    if (threadIdx.x == SCAN_BLOCK - 1) bsums[blockIdx.x] = tmp[threadIdx.x];
}

__global__ void scan2_kernel(int* __restrict__ bsums, int nb) {
    if (threadIdx.x == 0) {
        int run = 0;
        for (int i = 0; i < nb; ++i) { int t = bsums[i]; bsums[i] = run; run += t; }
    }
}

__global__ void scan3_kernel(int* __restrict__ cursor,
                             const int* __restrict__ bsums, int n) {
    int i = blockIdx.x * blockDim.x + threadIdx.x;
    if (i < n) cursor[i] += bsums[i / SCAN_BLOCK];
}

// ---------------------------------------------------------------------------
// CSR build phase 2: srcs[atomicAdd(cursor[dst])] = src
// (cursor ends at off[dst] + deg[dst]; aggregate recovers start as end - deg)
// ---------------------------------------------------------------------------
__global__ void fill_kernel(const int* __restrict__ ei32,
                            const long long* __restrict__ ei64,
                            const unsigned int* __restrict__ flag,
                            int* __restrict__ cursor,
                            int* __restrict__ srcs) {
    long e = (long)blockIdx.x * blockDim.x + threadIdx.x;
    if (e >= N_EDGES) return;
    int src, dst;
    if (*flag) {
        src = (int)ei64[e];
        dst = (int)ei64[N_EDGES + e];
    } else {
        src = ei32[e];
        dst = ei32[N_EDGES + e];
    }
    int p = atomicAdd(&cursor[dst], 1);
    srcs[p] = src;
}

// ---------------------------------------------------------------------------
// Gather aggregation + relu + W2 dot, 16 lanes per node (one channel each).
// ---------------------------------------------------------------------------
__global__ void aggregate_kernel(const int* __restrict__ srcs,
                                 const int* __restrict__ cursor,
                                 const int* __restrict__ deg,
                                 const float* __restrict__ h,
                                 const float* __restrict__ b1,
                                 const float* __restrict__ W2,
                                 const float* __restrict__ b2,
                                 float* __restrict__ out, int n) {
    int tid = blockIdx.x * blockDim.x + threadIdx.x;
    int node = tid >> 4;
    int c = tid & 15;
    if (node >= n) return;

    int end = cursor[node];
    int d = deg[node];
    int beg = end - d;

    float acc = 0.0f;
    for (int p = beg; p < end; ++p) {
        int s = srcs[p];                 // broadcast within the 16-lane group
        acc += h[(long)s * 16 + c];      // 64B coalesced line per group
    }

    float inv = 1.0f / fmaxf((float)d, 1.0f);
    float v = fmaxf(acc * inv + b1[c], 0.0f) * W2[c];
    v += __shfl_xor(v, 1);
    v += __shfl_xor(v, 2);
    v += __shfl_xor(v, 4);
    v += __shfl_xor(v, 8);
    if (c == 0) out[node] = v + b2[0];
}

// ---------------------------------------------------------------------------
// Fallback path (R0): atomic value scatter + finalize. Used if ws too small.
// ---------------------------------------------------------------------------
__global__ void scatter_kernel(const int* __restrict__ ei32,
                               const long long* __restrict__ ei64,
                               const unsigned int* __restrict__ flag,
                               const float* __restrict__ h,
                               float* __restrict__ summed,
                               float* __restrict__ cnt) {
    long e = (long)blockIdx.x * blockDim.x + threadIdx.x;
    if (e >= N_EDGES) return;
    long src, dst;
    if (*flag) { src = (long)ei64[e]; dst = (long)ei64[N_EDGES + e]; }
    else       { src = (long)ei32[e]; dst = (long)ei32[N_EDGES + e]; }
    const float4* hs = (const float4*)(h + src * 16);
    float4 a = hs[0], b = hs[1], c = hs[2], d = hs[3];
    float* o = summed + dst * 16;
    atomicAdd(o + 0,  a.x); atomicAdd(o + 1,  a.y);
    atomicAdd(o + 2,  a.z); atomicAdd(o + 3,  a.w);
    atomicAdd(o + 4,  b.x); atomicAdd(o + 5,  b.y);
    atomicAdd(o + 6,  b.z); atomicAdd(o + 7,  b.w);
    atomicAdd(o + 8,  c.x); atomicAdd(o + 9,  c.y);
    atomicAdd(o + 10, c.z); atomicAdd(o + 11, c.w);
    atomicAdd(o + 12, d.x); atomicAdd(o + 13, d.y);
    atomicAdd(o + 14, d.z); atomicAdd(o + 15, d.w);
    atomicAdd(cnt + dst, 1.0f);
}

__global__ void finalize_kernel(const float* __restrict__ summed,
                                const float* __restrict__ cnt,
                                const float* __restrict__ b1,
                                const float* __restrict__ W2,
                                const float* __restrict__ b2,
                                float* __restrict__ out, int n) {
    int i = blockIdx.x * blockDim.x + threadIdx.x;
    if (i >= n) return;
    const float4* s = (const float4*)(summed + (long)i * 16);
    float4 s0 = s[0], s1 = s[1], s2 = s[2], s3 = s[3];
    float sv[16] = {s0.x, s0.y, s0.z, s0.w, s1.x, s1.y, s1.z, s1.w,
                    s2.x, s2.y, s2.z, s2.w, s3.x, s3.y, s3.z, s3.w};
    float inv = 1.0f / fmaxf(cnt[i], 1.0f);
    float acc = b2[0];
#pragma unroll
    for (int c = 0; c < 16; ++c)
        acc += W2[c] * fmaxf(sv[c] * inv + b1[c], 0.0f);
    out[i] = acc;
}

extern "C" void kernel_launch(void* const* d_in, const int* in_sizes, int n_in,
                              void* d_out, int out_size, void* d_ws, size_t ws_size,
                              hipStream_t stream) {
    const float* x  = (const float*)d_in[0];
    const void*  ei = d_in[1];
    const float* W1 = (const float*)d_in[2];
    const float* b1 = (const float*)d_in[3];
    const float* W2 = (const float*)d_in[4];
    const float* b2 = (const float*)d_in[5];
    float* out = (float*)d_out;

    float* ws = (float*)d_ws;

    // CSR-path workspace layout (floats/ints, 4B each):
    //   h      : 1,600,000 f32
    //   srcs   : 3,200,000 i32
    //   deg    :   100,000 i32
    //   cursor :   100,000 i32
    //   bsums  :       256 i32
    //   flag   :         1 u32
    const size_t need_csr = (size_t)(1600000 + 3200000 + 100000 + 100000 + 256 + 1) * 4;

    if (ws_size >= need_csr) {
        float* h          = ws;
        int*   srcs       = (int*)(ws + 1600000);
        int*   deg        = (int*)(ws + 1600000 + 3200000);
        int*   cursor     = deg + N_NODES;
        int*   bsums      = cursor + N_NODES;
        unsigned int* flag = (unsigned int*)(bsums + 256);

        hipMemsetAsync(deg, 0, (size_t)N_NODES * sizeof(int), stream);

        detect_i64_kernel<<<1, 64, 0, stream>>>((const unsigned int*)ei, flag);

        linear1_kernel<<<(N_NODES + 127) / 128, 128, 0, stream>>>(x, W1, h, N_NODES);

        count_kernel<<<(N_EDGES + 255) / 256, 256, 0, stream>>>(
            (const int*)ei, (const long long*)ei, flag, deg);

        scan1_kernel<<<NB_SCAN, SCAN_BLOCK, 0, stream>>>(deg, cursor, bsums, N_NODES);
        scan2_kernel<<<1, 64, 0, stream>>>(bsums, NB_SCAN);
        scan3_kernel<<<(N_NODES + 255) / 256, 256, 0, stream>>>(cursor, bsums, N_NODES);

        fill_kernel<<<(N_EDGES + 255) / 256, 256, 0, stream>>>(
            (const int*)ei, (const long long*)ei, flag, cursor, srcs);

        aggregate_kernel<<<(N_NODES * 16 + 255) / 256, 256, 0, stream>>>(
            srcs, cursor, deg, h, b1, W2, b2, out, N_NODES);
    } else {
        // Fallback: R0 atomic-scatter path (13.2 MB workspace).
        float* h      = ws;                  // N_NODES * 16
        float* summed = ws + N_NODES * 16;   // N_NODES * 16
        float* cnt    = ws + N_NODES * 32;   // N_NODES
        unsigned int* flag = (unsigned int*)(ws + N_NODES * 33);

        hipMemsetAsync(summed, 0, (size_t)(N_NODES * 17) * sizeof(float), stream);
        detect_i64_kernel<<<1, 64, 0, stream>>>((const unsigned int*)ei, flag);
        linear1_kernel<<<(N_NODES + 127) / 128, 128, 0, stream>>>(x, W1, h, N_NODES);
        scatter_kernel<<<(N_EDGES + 255) / 256, 256, 0, stream>>>(
            (const int*)ei, (const long long*)ei, flag, h, summed, cnt);
        finalize_kernel<<<(N_NODES + 255) / 256, 256, 0, stream>>>(
            summed, cnt, b1, W2, b2, out, N_NODES);
    }
}

// Round 3
// 454.809 us; speedup vs baseline: 6.1159x; 1.2185x over previous
//
#include <hip/hip_runtime.h>

#define N_NODES 100000
#define N_EDGES 3200000
#define NBKT 391            // buckets of 256 nodes (dst >> 8)
#define EB 256              // phase-A blocks
#define EPB 12500           // edges per phase-A block (EB*EPB == N_EDGES)
#define SCAN_BLOCK 512
#define NSCAN (NBKT * EB)   // 100096 (bucket-major counts)
#define NB_SCAN ((NSCAN + SCAN_BLOCK - 1) / SCAN_BLOCK)  // 196

// ---------------------------------------------------------------------------
// Detect int64 vs int32 edge_index (odd 32-bit words all zero => int64).
// ---------------------------------------------------------------------------
__global__ void detect_i64_kernel(const unsigned int* __restrict__ ei,
                                  unsigned int* __restrict__ flag) {
    unsigned int v = 0;
    int lane = threadIdx.x;  // 64 threads
    for (int j = lane; j < 512; j += 64) v |= ei[2 * j + 1];
    unsigned long long any_nonzero = __ballot(v != 0u);
    if (lane == 0) *flag = (any_nonzero == 0ULL) ? 1u : 0u;
}

// ---------------------------------------------------------------------------
// h[i][c] = sum_k x[i][k] * W1[c][k]
// ---------------------------------------------------------------------------
__global__ void linear1_kernel(const float* __restrict__ x,
                               const float* __restrict__ W1,
                               float* __restrict__ h, int n) {
    __shared__ float w[16 * 58];
    for (int idx = threadIdx.x; idx < 16 * 58; idx += blockDim.x)
        w[idx] = W1[idx];
    __syncthreads();

    int i = blockIdx.x * blockDim.x + threadIdx.x;
    if (i >= n) return;

    float xv[58];
    const float* xr = x + (long)i * 58;
#pragma unroll
    for (int k = 0; k < 58; ++k) xv[k] = xr[k];

    float4 o[4];
#pragma unroll
    for (int q = 0; q < 4; ++q) {
        float a[4];
#pragma unroll
        for (int r = 0; r < 4; ++r) {
            int c = q * 4 + r;
            float acc = 0.0f;
#pragma unroll
            for (int k = 0; k < 58; ++k) acc += xv[k] * w[c * 58 + k];
            a[r] = acc;
        }
        o[q] = make_float4(a[0], a[1], a[2], a[3]);
    }
    float4* hr = (float4*)(h + (long)i * 16);
    hr[0] = o[0]; hr[1] = o[1]; hr[2] = o[2]; hr[3] = o[3];
}

// ---------------------------------------------------------------------------
// Phase A1: per-(bucket, block) histogram of dst buckets. LDS atomics only.
// bcount is bucket-major: bcount[bucket*EB + block].
// ---------------------------------------------------------------------------
__global__ void hist_kernel(const int* __restrict__ ei32,
                            const long long* __restrict__ ei64,
                            const unsigned int* __restrict__ flag,
                            int* __restrict__ bcount) {
    __shared__ int hist[NBKT];
    for (int i = threadIdx.x; i < NBKT; i += blockDim.x) hist[i] = 0;
    __syncthreads();

    long base = (long)blockIdx.x * EPB;
    bool i64 = (*flag != 0u);
    for (int k = threadIdx.x; k < EPB; k += blockDim.x) {
        long e = base + k;
        int dst = i64 ? (int)ei64[N_EDGES + e] : ei32[N_EDGES + e];
        atomicAdd(&hist[dst >> 8], 1);
    }
    __syncthreads();
    for (int b = threadIdx.x; b < NBKT; b += blockDim.x)
        bcount[(long)b * EB + blockIdx.x] = hist[b];
}

// ---------------------------------------------------------------------------
// In-place exclusive scan of bcount (NSCAN entries), 3 kernels.
// ---------------------------------------------------------------------------
__global__ void scan1_kernel(int* __restrict__ data,
                             int* __restrict__ bsums, int n) {
    __shared__ int tmp[SCAN_BLOCK];
    int i = blockIdx.x * SCAN_BLOCK + threadIdx.x;
    int v = (i < n) ? data[i] : 0;
    tmp[threadIdx.x] = v;
    __syncthreads();
#pragma unroll
    for (int d = 1; d < SCAN_BLOCK; d <<= 1) {
        int t = (threadIdx.x >= d) ? tmp[threadIdx.x - d] : 0;
        __syncthreads();
        tmp[threadIdx.x] += t;
        __syncthreads();
    }
    if (i < n) data[i] = tmp[threadIdx.x] - v;  // exclusive
    if (threadIdx.x == SCAN_BLOCK - 1) bsums[blockIdx.x] = tmp[threadIdx.x];
}

__global__ void scan2_kernel(int* __restrict__ bsums, int nb) {
    if (threadIdx.x == 0) {
        int run = 0;
        for (int i = 0; i < nb; ++i) { int t = bsums[i]; bsums[i] = run; run += t; }
    }
}

__global__ void scan3_kernel(int* __restrict__ data,
                             const int* __restrict__ bsums, int n) {
    int i = blockIdx.x * blockDim.x + threadIdx.x;
    if (i < n) data[i] += bsums[i / SCAN_BLOCK];
}

// ---------------------------------------------------------------------------
// Phase A2: scatter each edge into its bucket region as a packed word:
// (dst & 255) << 17 | src.  Slots come from LDS cursors (per-block regions),
// so global writes are dense ~128B runs owned by one block.
// ---------------------------------------------------------------------------
__global__ void bucket_scatter_kernel(const int* __restrict__ ei32,
                                      const long long* __restrict__ ei64,
                                      const unsigned int* __restrict__ flag,
                                      const int* __restrict__ boffs,
                                      unsigned int* __restrict__ packed) {
    __shared__ int cur[NBKT];
    for (int i = threadIdx.x; i < NBKT; i += blockDim.x)
        cur[i] = boffs[(long)i * EB + blockIdx.x];
    __syncthreads();

    long base = (long)blockIdx.x * EPB;
    bool i64 = (*flag != 0u);
    for (int k = threadIdx.x; k < EPB; k += blockDim.x) {
        long e = base + k;
        int src, dst;
        if (i64) { src = (int)ei64[e]; dst = (int)ei64[N_EDGES + e]; }
        else     { src = ei32[e];      dst = ei32[N_EDGES + e]; }
        int p = atomicAdd(&cur[dst >> 8], 1);
        packed[p] = ((unsigned int)(dst & 255) << 17) | (unsigned int)src;
    }
}

// ---------------------------------------------------------------------------
// Phase B: one block per bucket. Accumulate sums[256][17] + cnt[256] in LDS
// (quarter-wave per edge: lane c handles channel c), then fused
// mean + bias + relu + W2-dot + b2 straight to out. Zero global atomics.
// ---------------------------------------------------------------------------
__global__ void bucket_aggregate_kernel(const unsigned int* __restrict__ packed,
                                        const int* __restrict__ boffs,
                                        const float* __restrict__ h,
                                        const float* __restrict__ b1,
                                        const float* __restrict__ W2,
                                        const float* __restrict__ b2,
                                        float* __restrict__ out) {
    __shared__ float sums[256 * 17];   // stride 17: conflict-free finalize
    __shared__ int cnt[256];

    int b = blockIdx.x;
    for (int i = threadIdx.x; i < 256 * 17; i += blockDim.x) sums[i] = 0.0f;
    if (threadIdx.x < 256) cnt[threadIdx.x] = 0;
    __syncthreads();

    int start = boffs[(long)b * EB];
    int end = (b + 1 < NBKT) ? boffs[(long)(b + 1) * EB] : N_EDGES;

    int sub = threadIdx.x & 15;           // channel
    for (int e = start + (threadIdx.x >> 4); e < end; e += (int)(blockDim.x >> 4)) {
        unsigned int v = packed[e];
        int src = (int)(v & 0x1FFFFu);
        int ld  = (int)(v >> 17);
        atomicAdd(&sums[ld * 17 + sub], h[(long)src * 16 + sub]);
        if (sub == 0) atomicAdd(&cnt[ld], 1);
    }
    __syncthreads();

    int t = threadIdx.x;                  // 256 threads = 256 nodes
    int g = b * 256 + t;
    if (g < N_NODES) {
        float inv = 1.0f / fmaxf((float)cnt[t], 1.0f);
        float acc = b2[0];
#pragma unroll
        for (int c = 0; c < 16; ++c)
            acc += W2[c] * fmaxf(sums[t * 17 + c] * inv + b1[c], 0.0f);
        out[g] = acc;
    }
}

// ---------------------------------------------------------------------------
// Fallback path (R0): atomic value scatter + finalize. Used if ws too small.
// ---------------------------------------------------------------------------
__global__ void scatter_kernel(const int* __restrict__ ei32,
                               const long long* __restrict__ ei64,
                               const unsigned int* __restrict__ flag,
                               const float* __restrict__ h,
                               float* __restrict__ summed,
                               float* __restrict__ cnt) {
    long e = (long)blockIdx.x * blockDim.x + threadIdx.x;
    if (e >= N_EDGES) return;
    long src, dst;
    if (*flag) { src = (long)ei64[e]; dst = (long)ei64[N_EDGES + e]; }
    else       { src = (long)ei32[e]; dst = (long)ei32[N_EDGES + e]; }
    const float4* hs = (const float4*)(h + src * 16);
    float4 a = hs[0], b = hs[1], c = hs[2], d = hs[3];
    float* o = summed + dst * 16;
    atomicAdd(o + 0,  a.x); atomicAdd(o + 1,  a.y);
    atomicAdd(o + 2,  a.z); atomicAdd(o + 3,  a.w);
    atomicAdd(o + 4,  b.x); atomicAdd(o + 5,  b.y);
    atomicAdd(o + 6,  b.z); atomicAdd(o + 7,  b.w);
    atomicAdd(o + 8,  c.x); atomicAdd(o + 9,  c.y);
    atomicAdd(o + 10, c.z); atomicAdd(o + 11, c.w);
    atomicAdd(o + 12, d.x); atomicAdd(o + 13, d.y);
    atomicAdd(o + 14, d.z); atomicAdd(o + 15, d.w);
    atomicAdd(cnt + dst, 1.0f);
}

__global__ void finalize_kernel(const float* __restrict__ summed,
                                const float* __restrict__ cnt,
                                const float* __restrict__ b1,
                                const float* __restrict__ W2,
                                const float* __restrict__ b2,
                                float* __restrict__ out, int n) {
    int i = blockIdx.x * blockDim.x + threadIdx.x;
    if (i >= n) return;
    const float4* s = (const float4*)(summed + (long)i * 16);
    float4 s0 = s[0], s1 = s[1], s2 = s[2], s3 = s[3];
    float sv[16] = {s0.x, s0.y, s0.z, s0.w, s1.x, s1.y, s1.z, s1.w,
                    s2.x, s2.y, s2.z, s2.w, s3.x, s3.y, s3.z, s3.w};
    float inv = 1.0f / fmaxf(cnt[i], 1.0f);
    float acc = b2[0];
#pragma unroll
    for (int c = 0; c < 16; ++c)
        acc += W2[c] * fmaxf(sv[c] * inv + b1[c], 0.0f);
    out[i] = acc;
}

extern "C" void kernel_launch(void* const* d_in, const int* in_sizes, int n_in,
                              void* d_out, int out_size, void* d_ws, size_t ws_size,
                              hipStream_t stream) {
    const float* x  = (const float*)d_in[0];
    const void*  ei = d_in[1];
    const float* W1 = (const float*)d_in[2];
    const float* b1 = (const float*)d_in[3];
    const float* W2 = (const float*)d_in[4];
    const float* b2 = (const float*)d_in[5];
    float* out = (float*)d_out;

    float* ws = (float*)d_ws;

    // Bucket-path workspace (4B words):
    //   h      : 1,600,000 f32
    //   packed : 3,200,000 u32
    //   bcount : NSCAN (100,096) i32   (scanned in place -> offsets)
    //   bsums  : 256 i32
    //   flag   : 1 u32
    const size_t need_bkt = (size_t)(1600000 + 3200000 + NSCAN + 256 + 1) * 4;

    if (ws_size >= need_bkt) {
        float*        h      = ws;
        unsigned int* packed = (unsigned int*)(ws + 1600000);
        int*          bcount = (int*)(ws + 1600000 + 3200000);
        int*          bsums  = bcount + NSCAN;
        unsigned int* flag   = (unsigned int*)(bsums + 256);

        detect_i64_kernel<<<1, 64, 0, stream>>>((const unsigned int*)ei, flag);

        linear1_kernel<<<(N_NODES + 127) / 128, 128, 0, stream>>>(x, W1, h, N_NODES);

        hist_kernel<<<EB, 256, 0, stream>>>(
            (const int*)ei, (const long long*)ei, flag, bcount);

        scan1_kernel<<<NB_SCAN, SCAN_BLOCK, 0, stream>>>(bcount, bsums, NSCAN);
        scan2_kernel<<<1, 64, 0, stream>>>(bsums, NB_SCAN);
        scan3_kernel<<<(NSCAN + 255) / 256, 256, 0, stream>>>(bcount, bsums, NSCAN);

        bucket_scatter_kernel<<<EB, 256, 0, stream>>>(
            (const int*)ei, (const long long*)ei, flag, bcount, packed);

        bucket_aggregate_kernel<<<NBKT, 256, 0, stream>>>(
            packed, bcount, h, b1, W2, b2, out);
    } else {
        // Fallback: R0 atomic-scatter path (13.2 MB workspace).
        float* h      = ws;                  // N_NODES * 16
        float* summed = ws + N_NODES * 16;   // N_NODES * 16
        float* cnt    = ws + N_NODES * 32;   // N_NODES
        unsigned int* flag = (unsigned int*)(ws + N_NODES * 33);

        hipMemsetAsync(summed, 0, (size_t)(N_NODES * 17) * sizeof(float), stream);
        detect_i64_kernel<<<1, 64, 0, stream>>>((const unsigned int*)ei, flag);
        linear1_kernel<<<(N_NODES + 127) / 128, 128, 0, stream>>>(x, W1, h, N_NODES);
        scatter_kernel<<<(N_EDGES + 255) / 256, 256, 0, stream>>>(
            (const int*)ei, (const long long*)ei, flag, h, summed, cnt);
        finalize_kernel<<<(N_NODES + 255) / 256, 256, 0, stream>>>(
            summed, cnt, b1, W2, b2, out, N_NODES);
    }
}

// Round 4
// 416.325 us; speedup vs baseline: 6.6812x; 1.0924x over previous
//
#include <hip/hip_runtime.h>

#define N_NODES 100000
#define N_EDGES 3200000
#define NBKT 391            // buckets of 256 nodes (dst >> 8)
#define EB 256              // phase-A blocks
#define EPB 12500           // edges per phase-A block (EB*EPB == N_EDGES)
#define SCAN_BLOCK 512
#define NSCAN (NBKT * EB)   // 100096 (bucket-major counts)
#define NB_SCAN ((NSCAN + SCAN_BLOCK - 1) / SCAN_BLOCK)  // 196 (<= 256)

// ---------------------------------------------------------------------------
// Detect int64 vs int32 edge_index (odd 32-bit words all zero => int64).
// ---------------------------------------------------------------------------
__global__ void detect_i64_kernel(const unsigned int* __restrict__ ei,
                                  unsigned int* __restrict__ flag) {
    unsigned int v = 0;
    int lane = threadIdx.x;  // 64 threads
    for (int j = lane; j < 512; j += 64) v |= ei[2 * j + 1];
    unsigned long long any_nonzero = __ballot(v != 0u);
    if (lane == 0) *flag = (any_nonzero == 0ULL) ? 1u : 0u;
}

// ---------------------------------------------------------------------------
// h[i][c] = sum_k x[i][k] * W1[c][k]
// ---------------------------------------------------------------------------
__global__ void linear1_kernel(const float* __restrict__ x,
                               const float* __restrict__ W1,
                               float* __restrict__ h, int n) {
    __shared__ float w[16 * 58];
    for (int idx = threadIdx.x; idx < 16 * 58; idx += blockDim.x)
        w[idx] = W1[idx];
    __syncthreads();

    int i = blockIdx.x * blockDim.x + threadIdx.x;
    if (i >= n) return;

    float xv[58];
    const float* xr = x + (long)i * 58;
#pragma unroll
    for (int k = 0; k < 58; ++k) xv[k] = xr[k];

    float4 o[4];
#pragma unroll
    for (int q = 0; q < 4; ++q) {
        float a[4];
#pragma unroll
        for (int r = 0; r < 4; ++r) {
            int c = q * 4 + r;
            float acc = 0.0f;
#pragma unroll
            for (int k = 0; k < 58; ++k) acc += xv[k] * w[c * 58 + k];
            a[r] = acc;
        }
        o[q] = make_float4(a[0], a[1], a[2], a[3]);
    }
    float4* hr = (float4*)(h + (long)i * 16);
    hr[0] = o[0]; hr[1] = o[1]; hr[2] = o[2]; hr[3] = o[3];
}

// ---------------------------------------------------------------------------
// Phase A1: per-(bucket, block) histogram of dst buckets. LDS atomics only.
// bcount is bucket-major: bcount[bucket*EB + block].
// ---------------------------------------------------------------------------
__global__ void hist_kernel(const int* __restrict__ ei32,
                            const long long* __restrict__ ei64,
                            const unsigned int* __restrict__ flag,
                            int* __restrict__ bcount) {
    __shared__ int hist[NBKT];
    for (int i = threadIdx.x; i < NBKT; i += blockDim.x) hist[i] = 0;
    __syncthreads();

    long base = (long)blockIdx.x * EPB;
    bool i64 = (*flag != 0u);
    for (int k = threadIdx.x; k < EPB; k += blockDim.x) {
        long e = base + k;
        int dst = i64 ? (int)ei64[N_EDGES + e] : ei32[N_EDGES + e];
        atomicAdd(&hist[dst >> 8], 1);
    }
    __syncthreads();
    for (int b = threadIdx.x; b < NBKT; b += blockDim.x)
        bcount[(long)b * EB + blockIdx.x] = hist[b];
}

// ---------------------------------------------------------------------------
// In-place exclusive scan of bcount (NSCAN entries), 3 kernels.
// ---------------------------------------------------------------------------
__global__ void scan1_kernel(int* __restrict__ data,
                             int* __restrict__ bsums, int n) {
    __shared__ int tmp[SCAN_BLOCK];
    int i = blockIdx.x * SCAN_BLOCK + threadIdx.x;
    int v = (i < n) ? data[i] : 0;
    tmp[threadIdx.x] = v;
    __syncthreads();
#pragma unroll
    for (int d = 1; d < SCAN_BLOCK; d <<= 1) {
        int t = (threadIdx.x >= d) ? tmp[threadIdx.x - d] : 0;
        __syncthreads();
        tmp[threadIdx.x] += t;
        __syncthreads();
    }
    if (i < n) data[i] = tmp[threadIdx.x] - v;  // exclusive
    if (threadIdx.x == SCAN_BLOCK - 1) bsums[blockIdx.x] = tmp[threadIdx.x];
}

// Parallel LDS exclusive scan of the (<=256) block sums — replaces the
// single-thread serial scan (196 dependent L2 round-trips, ~30us).
__global__ void scan2_kernel(int* __restrict__ bsums, int nb) {
    __shared__ int tmp[256];
    int i = threadIdx.x;
    int v = (i < nb) ? bsums[i] : 0;
    tmp[i] = v;
    __syncthreads();
#pragma unroll
    for (int d = 1; d < 256; d <<= 1) {
        int t = (i >= d) ? tmp[i - d] : 0;
        __syncthreads();
        tmp[i] += t;
        __syncthreads();
    }
    if (i < nb) bsums[i] = tmp[i] - v;  // exclusive
}

__global__ void scan3_kernel(int* __restrict__ data,
                             const int* __restrict__ bsums, int n) {
    int i = blockIdx.x * blockDim.x + threadIdx.x;
    if (i < n) data[i] += bsums[i / SCAN_BLOCK];
}

// ---------------------------------------------------------------------------
// Phase A2: scatter each edge into its bucket region as a packed word:
// (dst & 255) << 17 | src.  Slots come from LDS cursors (per-block regions),
// so global writes are dense runs owned by one block.
// ---------------------------------------------------------------------------
__global__ void bucket_scatter_kernel(const int* __restrict__ ei32,
                                      const long long* __restrict__ ei64,
                                      const unsigned int* __restrict__ flag,
                                      const int* __restrict__ boffs,
                                      unsigned int* __restrict__ packed) {
    __shared__ int cur[NBKT];
    for (int i = threadIdx.x; i < NBKT; i += blockDim.x)
        cur[i] = boffs[(long)i * EB + blockIdx.x];
    __syncthreads();

    long base = (long)blockIdx.x * EPB;
    bool i64 = (*flag != 0u);
    for (int k = threadIdx.x; k < EPB; k += blockDim.x) {
        long e = base + k;
        int src, dst;
        if (i64) { src = (int)ei64[e]; dst = (int)ei64[N_EDGES + e]; }
        else     { src = ei32[e];      dst = ei32[N_EDGES + e]; }
        int p = atomicAdd(&cur[dst >> 8], 1);
        packed[p] = ((unsigned int)(dst & 255) << 17) | (unsigned int)src;
    }
}

// ---------------------------------------------------------------------------
// Phase B: one 1024-thread block per bucket (16 waves for latency hiding).
// Accumulate sums[256][17] + cnt[256] in LDS (16 lanes = 16 channels per
// edge, unroll-2 for ILP), then fused mean + bias + relu + W2-dot + b2.
// ---------------------------------------------------------------------------
__global__ void __launch_bounds__(1024, 2)
bucket_aggregate_kernel(const unsigned int* __restrict__ packed,
                        const int* __restrict__ boffs,
                        const float* __restrict__ h,
                        const float* __restrict__ b1,
                        const float* __restrict__ W2,
                        const float* __restrict__ b2,
                        float* __restrict__ out) {
    __shared__ float sums[256 * 17];   // stride 17: conflict-free finalize
    __shared__ int cnt[256];

    int b = blockIdx.x;
    for (int i = threadIdx.x; i < 256 * 17; i += blockDim.x) sums[i] = 0.0f;
    if (threadIdx.x < 256) cnt[threadIdx.x] = 0;
    __syncthreads();

    int start = boffs[(long)b * EB];
    int end = (b + 1 < NBKT) ? boffs[(long)(b + 1) * EB] : N_EDGES;

    int sub = threadIdx.x & 15;             // channel
    int stride = (int)(blockDim.x >> 4);    // 64 edge-groups
    int e = start + (int)(threadIdx.x >> 4);

    // unroll-2: two independent gathers in flight per thread
    for (; e + stride < end; e += 2 * stride) {
        unsigned int v0 = packed[e];
        unsigned int v1 = packed[e + stride];
        int s0 = (int)(v0 & 0x1FFFFu), l0 = (int)(v0 >> 17);
        int s1 = (int)(v1 & 0x1FFFFu), l1 = (int)(v1 >> 17);
        float h0 = h[(long)s0 * 16 + sub];
        float h1 = h[(long)s1 * 16 + sub];
        atomicAdd(&sums[l0 * 17 + sub], h0);
        atomicAdd(&sums[l1 * 17 + sub], h1);
        if (sub == 0) { atomicAdd(&cnt[l0], 1); atomicAdd(&cnt[l1], 1); }
    }
    if (e < end) {
        unsigned int v = packed[e];
        int s = (int)(v & 0x1FFFFu), ld = (int)(v >> 17);
        atomicAdd(&sums[ld * 17 + sub], h[(long)s * 16 + sub]);
        if (sub == 0) atomicAdd(&cnt[ld], 1);
    }
    __syncthreads();

    int t = threadIdx.x;                  // first 256 threads = 256 nodes
    int g = b * 256 + t;
    if (t < 256 && g < N_NODES) {
        float inv = 1.0f / fmaxf((float)cnt[t], 1.0f);
        float acc = b2[0];
#pragma unroll
        for (int c = 0; c < 16; ++c)
            acc += W2[c] * fmaxf(sums[t * 17 + c] * inv + b1[c], 0.0f);
        out[g] = acc;
    }
}

// ---------------------------------------------------------------------------
// Fallback path (R0): atomic value scatter + finalize. Used if ws too small.
// ---------------------------------------------------------------------------
__global__ void scatter_kernel(const int* __restrict__ ei32,
                               const long long* __restrict__ ei64,
                               const unsigned int* __restrict__ flag,
                               const float* __restrict__ h,
                               float* __restrict__ summed,
                               float* __restrict__ cnt) {
    long e = (long)blockIdx.x * blockDim.x + threadIdx.x;
    if (e >= N_EDGES) return;
    long src, dst;
    if (*flag) { src = (long)ei64[e]; dst = (long)ei64[N_EDGES + e]; }
    else       { src = (long)ei32[e]; dst = (long)ei32[N_EDGES + e]; }
    const float4* hs = (const float4*)(h + src * 16);
    float4 a = hs[0], b = hs[1], c = hs[2], d = hs[3];
    float* o = summed + dst * 16;
    atomicAdd(o + 0,  a.x); atomicAdd(o + 1,  a.y);
    atomicAdd(o + 2,  a.z); atomicAdd(o + 3,  a.w);
    atomicAdd(o + 4,  b.x); atomicAdd(o + 5,  b.y);
    atomicAdd(o + 6,  b.z); atomicAdd(o + 7,  b.w);
    atomicAdd(o + 8,  c.x); atomicAdd(o + 9,  c.y);
    atomicAdd(o + 10, c.z); atomicAdd(o + 11, c.w);
    atomicAdd(o + 12, d.x); atomicAdd(o + 13, d.y);
    atomicAdd(o + 14, d.z); atomicAdd(o + 15, d.w);
    atomicAdd(cnt + dst, 1.0f);
}

__global__ void finalize_kernel(const float* __restrict__ summed,
                                const float* __restrict__ cnt,
                                const float* __restrict__ b1,
                                const float* __restrict__ W2,
                                const float* __restrict__ b2,
                                float* __restrict__ out, int n) {
    int i = blockIdx.x * blockDim.x + threadIdx.x;
    if (i >= n) return;
    const float4* s = (const float4*)(summed + (long)i * 16);
    float4 s0 = s[0], s1 = s[1], s2 = s[2], s3 = s[3];
    float sv[16] = {s0.x, s0.y, s0.z, s0.w, s1.x, s1.y, s1.z, s1.w,
                    s2.x, s2.y, s2.z, s2.w, s3.x, s3.y, s3.z, s3.w};
    float inv = 1.0f / fmaxf(cnt[i], 1.0f);
    float acc = b2[0];
#pragma unroll
    for (int c = 0; c < 16; ++c)
        acc += W2[c] * fmaxf(sv[c] * inv + b1[c], 0.0f);
    out[i] = acc;
}

extern "C" void kernel_launch(void* const* d_in, const int* in_sizes, int n_in,
                              void* d_out, int out_size, void* d_ws, size_t ws_size,
                              hipStream_t stream) {
    const float* x  = (const float*)d_in[0];
    const void*  ei = d_in[1];
    const float* W1 = (const float*)d_in[2];
    const float* b1 = (const float*)d_in[3];
    const float* W2 = (const float*)d_in[4];
    const float* b2 = (const float*)d_in[5];
    float* out = (float*)d_out;

    float* ws = (float*)d_ws;

    // Bucket-path workspace (4B words):
    //   h      : 1,600,000 f32
    //   packed : 3,200,000 u32
    //   bcount : NSCAN (100,096) i32   (scanned in place -> offsets)
    //   bsums  : 256 i32
    //   flag   : 1 u32
    const size_t need_bkt = (size_t)(1600000 + 3200000 + NSCAN + 256 + 1) * 4;

    if (ws_size >= need_bkt) {
        float*        h      = ws;
        unsigned int* packed = (unsigned int*)(ws + 1600000);
        int*          bcount = (int*)(ws + 1600000 + 3200000);
        int*          bsums  = bcount + NSCAN;
        unsigned int* flag   = (unsigned int*)(bsums + 256);

        detect_i64_kernel<<<1, 64, 0, stream>>>((const unsigned int*)ei, flag);

        linear1_kernel<<<(N_NODES + 127) / 128, 128, 0, stream>>>(x, W1, h, N_NODES);

        hist_kernel<<<EB, 512, 0, stream>>>(
            (const int*)ei, (const long long*)ei, flag, bcount);

        scan1_kernel<<<NB_SCAN, SCAN_BLOCK, 0, stream>>>(bcount, bsums, NSCAN);
        scan2_kernel<<<1, 256, 0, stream>>>(bsums, NB_SCAN);
        scan3_kernel<<<(NSCAN + 255) / 256, 256, 0, stream>>>(bcount, bsums, NSCAN);

        bucket_scatter_kernel<<<EB, 512, 0, stream>>>(
            (const int*)ei, (const long long*)ei, flag, bcount, packed);

        bucket_aggregate_kernel<<<NBKT, 1024, 0, stream>>>(
            packed, bcount, h, b1, W2, b2, out);
    } else {
        // Fallback: R0 atomic-scatter path (13.2 MB workspace).
        float* h      = ws;                  // N_NODES * 16
        float* summed = ws + N_NODES * 16;   // N_NODES * 16
        float* cnt    = ws + N_NODES * 32;   // N_NODES
        unsigned int* flag = (unsigned int*)(ws + N_NODES * 33);

        hipMemsetAsync(summed, 0, (size_t)(N_NODES * 17) * sizeof(float), stream);
        detect_i64_kernel<<<1, 64, 0, stream>>>((const unsigned int*)ei, flag);
        linear1_kernel<<<(N_NODES + 127) / 128, 128, 0, stream>>>(x, W1, h, N_NODES);
        scatter_kernel<<<(N_EDGES + 255) / 256, 256, 0, stream>>>(
            (const int*)ei, (const long long*)ei, flag, h, summed, cnt);
        finalize_kernel<<<(N_NODES + 255) / 256, 256, 0, stream>>>(
            summed, cnt, b1, W2, b2, out, N_NODES);
    }
}

// Round 5
// 413.023 us; speedup vs baseline: 6.7346x; 1.0080x over previous
//
#include <hip/hip_runtime.h>
#include <hip/hip_fp16.h>

#define N_NODES 100000
#define N_EDGES 3200000
#define NBKT 782            // buckets of 128 nodes (dst >> 7)
#define EB 256              // phase-A blocks
#define EPB 12500           // edges per phase-A block (EB*EPB == N_EDGES)
#define SCAN_BLOCK 512
#define NSCAN (NBKT * EB)   // 200192 (bucket-major counts)
#define NB_SCAN ((NSCAN + SCAN_BLOCK - 1) / SCAN_BLOCK)  // 391 (<= 512)

// ---------------------------------------------------------------------------
// Detect int64 vs int32 edge_index (odd 32-bit words all zero => int64).
// ---------------------------------------------------------------------------
__global__ void detect_i64_kernel(const unsigned int* __restrict__ ei,
                                  unsigned int* __restrict__ flag) {
    unsigned int v = 0;
    int lane = threadIdx.x;  // 64 threads
    for (int j = lane; j < 512; j += 64) v |= ei[2 * j + 1];
    unsigned long long any_nonzero = __ballot(v != 0u);
    if (lane == 0) *flag = (any_nonzero == 0ULL) ? 1u : 0u;
}

// ---------------------------------------------------------------------------
// h2[i][c] = fp16( sum_k x[i][k] * W1[c][k] )  -- h stored as __half2[N][8]
// (3.2 MB: fits in every XCD's 4 MiB L2 -> gathers become L2 hits)
// ---------------------------------------------------------------------------
__global__ void linear1_kernel(const float* __restrict__ x,
                               const float* __restrict__ W1,
                               __half2* __restrict__ h2, int n) {
    __shared__ float w[16 * 58];
    for (int idx = threadIdx.x; idx < 16 * 58; idx += blockDim.x)
        w[idx] = W1[idx];
    __syncthreads();

    int i = blockIdx.x * blockDim.x + threadIdx.x;
    if (i >= n) return;

    float xv[58];
    const float* xr = x + (long)i * 58;
#pragma unroll
    for (int k = 0; k < 58; ++k) xv[k] = xr[k];

    __half2 o[8];
#pragma unroll
    for (int q = 0; q < 8; ++q) {
        float a[2];
#pragma unroll
        for (int r = 0; r < 2; ++r) {
            int c = q * 2 + r;
            float acc = 0.0f;
#pragma unroll
            for (int k = 0; k < 58; ++k) acc += xv[k] * w[c * 58 + k];
            a[r] = acc;
        }
        o[q] = __floats2half2_rn(a[0], a[1]);
    }
    // 32B per row, aligned; write as two 16B stores
    float4* dst = (float4*)(h2 + (long)i * 8);
    float4* src = (float4*)o;
    dst[0] = src[0];
    dst[1] = src[1];
}

// ---------------------------------------------------------------------------
// Phase A1: per-(bucket, block) histogram of dst buckets. LDS atomics only.
// bcount is bucket-major: bcount[bucket*EB + block].
// ---------------------------------------------------------------------------
__global__ void hist_kernel(const int* __restrict__ ei32,
                            const long long* __restrict__ ei64,
                            const unsigned int* __restrict__ flag,
                            int* __restrict__ bcount) {
    __shared__ int hist[NBKT];
    for (int i = threadIdx.x; i < NBKT; i += blockDim.x) hist[i] = 0;
    __syncthreads();

    long base = (long)blockIdx.x * EPB;
    bool i64 = (*flag != 0u);
    for (int k = threadIdx.x; k < EPB; k += blockDim.x) {
        long e = base + k;
        int dst = i64 ? (int)ei64[N_EDGES + e] : ei32[N_EDGES + e];
        atomicAdd(&hist[dst >> 7], 1);
    }
    __syncthreads();
    for (int b = threadIdx.x; b < NBKT; b += blockDim.x)
        bcount[(long)b * EB + blockIdx.x] = hist[b];
}

// ---------------------------------------------------------------------------
// In-place exclusive scan of bcount (NSCAN entries), 3 kernels.
// ---------------------------------------------------------------------------
__global__ void scan1_kernel(int* __restrict__ data,
                             int* __restrict__ bsums, int n) {
    __shared__ int tmp[SCAN_BLOCK];
    int i = blockIdx.x * SCAN_BLOCK + threadIdx.x;
    int v = (i < n) ? data[i] : 0;
    tmp[threadIdx.x] = v;
    __syncthreads();
#pragma unroll
    for (int d = 1; d < SCAN_BLOCK; d <<= 1) {
        int t = (threadIdx.x >= d) ? tmp[threadIdx.x - d] : 0;
        __syncthreads();
        tmp[threadIdx.x] += t;
        __syncthreads();
    }
    if (i < n) data[i] = tmp[threadIdx.x] - v;  // exclusive
    if (threadIdx.x == SCAN_BLOCK - 1) bsums[blockIdx.x] = tmp[threadIdx.x];
}

// Parallel LDS exclusive scan of the (<=512) block sums.
__global__ void scan2_kernel(int* __restrict__ bsums, int nb) {
    __shared__ int tmp[512];
    int i = threadIdx.x;
    int v = (i < nb) ? bsums[i] : 0;
    tmp[i] = v;
    __syncthreads();
#pragma unroll
    for (int d = 1; d < 512; d <<= 1) {
        int t = (i >= d) ? tmp[i - d] : 0;
        __syncthreads();
        tmp[i] += t;
        __syncthreads();
    }
    if (i < nb) bsums[i] = tmp[i] - v;  // exclusive
}

__global__ void scan3_kernel(int* __restrict__ data,
                             const int* __restrict__ bsums, int n) {
    int i = blockIdx.x * blockDim.x + threadIdx.x;
    if (i < n) data[i] += bsums[i / SCAN_BLOCK];
}

// ---------------------------------------------------------------------------
// Phase A2: scatter each edge into its bucket region as a packed word:
// (dst & 127) << 17 | src.  Slots come from LDS cursors (per-block regions),
// so global writes are dense runs owned by one block.
// ---------------------------------------------------------------------------
__global__ void bucket_scatter_kernel(const int* __restrict__ ei32,
                                      const long long* __restrict__ ei64,
                                      const unsigned int* __restrict__ flag,
                                      const int* __restrict__ boffs,
                                      unsigned int* __restrict__ packed) {
    __shared__ int cur[NBKT];
    for (int i = threadIdx.x; i < NBKT; i += blockDim.x)
        cur[i] = boffs[(long)i * EB + blockIdx.x];
    __syncthreads();

    long base = (long)blockIdx.x * EPB;
    bool i64 = (*flag != 0u);
    for (int k = threadIdx.x; k < EPB; k += blockDim.x) {
        long e = base + k;
        int src, dst;
        if (i64) { src = (int)ei64[e]; dst = (int)ei64[N_EDGES + e]; }
        else     { src = ei32[e];      dst = ei32[N_EDGES + e]; }
        int p = atomicAdd(&cur[dst >> 7], 1);
        packed[p] = ((unsigned int)(dst & 127) << 17) | (unsigned int)src;
    }
}

// ---------------------------------------------------------------------------
// Phase B: one 512-thread block per 128-node bucket. 8 lanes per edge, each
// lane loads one __half2 (2 channels, 4B) -> 8 edges per wave instruction.
// Unroll-4 keeps 4 gathers in flight. Fused mean+bias+relu+W2-dot epilogue.
// ---------------------------------------------------------------------------
__global__ void __launch_bounds__(512, 4)
bucket_aggregate_kernel(const unsigned int* __restrict__ packed,
                        const int* __restrict__ boffs,
                        const __half2* __restrict__ h2,
                        const float* __restrict__ b1,
                        const float* __restrict__ W2,
                        const float* __restrict__ b2,
                        float* __restrict__ out) {
    __shared__ float sums[128 * 17];   // stride 17: conflict-spread
    __shared__ int cnt[128];

    int b = blockIdx.x;
    for (int i = threadIdx.x; i < 128 * 17; i += blockDim.x) sums[i] = 0.0f;
    if (threadIdx.x < 128) cnt[threadIdx.x] = 0;
    __syncthreads();

    int start = boffs[(long)b * EB];
    int end = (b + 1 < NBKT) ? boffs[(long)(b + 1) * EB] : N_EDGES;

    int c = threadIdx.x & 7;                // channel-pair index (0..7)
    int stride = (int)(blockDim.x >> 3);    // 64 edge-groups
    int e = start + (int)(threadIdx.x >> 3);

    // unroll-4: four independent gathers in flight per thread
    for (; e + 3 * stride < end; e += 4 * stride) {
        unsigned int v0 = packed[e];
        unsigned int v1 = packed[e + stride];
        unsigned int v2 = packed[e + 2 * stride];
        unsigned int v3 = packed[e + 3 * stride];
        int s0 = (int)(v0 & 0x1FFFFu), l0 = (int)(v0 >> 17);
        int s1 = (int)(v1 & 0x1FFFFu), l1 = (int)(v1 >> 17);
        int s2 = (int)(v2 & 0x1FFFFu), l2 = (int)(v2 >> 17);
        int s3 = (int)(v3 & 0x1FFFFu), l3 = (int)(v3 >> 17);
        float2 f0 = __half22float2(h2[(long)s0 * 8 + c]);
        float2 f1 = __half22float2(h2[(long)s1 * 8 + c]);
        float2 f2 = __half22float2(h2[(long)s2 * 8 + c]);
        float2 f3 = __half22float2(h2[(long)s3 * 8 + c]);
        atomicAdd(&sums[l0 * 17 + 2 * c],     f0.x);
        atomicAdd(&sums[l0 * 17 + 2 * c + 1], f0.y);
        atomicAdd(&sums[l1 * 17 + 2 * c],     f1.x);
        atomicAdd(&sums[l1 * 17 + 2 * c + 1], f1.y);
        atomicAdd(&sums[l2 * 17 + 2 * c],     f2.x);
        atomicAdd(&sums[l2 * 17 + 2 * c + 1], f2.y);
        atomicAdd(&sums[l3 * 17 + 2 * c],     f3.x);
        atomicAdd(&sums[l3 * 17 + 2 * c + 1], f3.y);
        if (c == 0) {
            atomicAdd(&cnt[l0], 1); atomicAdd(&cnt[l1], 1);
            atomicAdd(&cnt[l2], 1); atomicAdd(&cnt[l3], 1);
        }
    }
    for (; e < end; e += stride) {
        unsigned int v = packed[e];
        int s = (int)(v & 0x1FFFFu), ld = (int)(v >> 17);
        float2 f = __half22float2(h2[(long)s * 8 + c]);
        atomicAdd(&sums[ld * 17 + 2 * c],     f.x);
        atomicAdd(&sums[ld * 17 + 2 * c + 1], f.y);
        if (c == 0) atomicAdd(&cnt[ld], 1);
    }
    __syncthreads();

    int t = threadIdx.x;                  // first 128 threads = 128 nodes
    int g = b * 128 + t;
    if (t < 128 && g < N_NODES) {
        float inv = 1.0f / fmaxf((float)cnt[t], 1.0f);
        float acc = b2[0];
#pragma unroll
        for (int ch = 0; ch < 16; ++ch)
            acc += W2[ch] * fmaxf(sums[t * 17 + ch] * inv + b1[ch], 0.0f);
        out[g] = acc;
    }
}

// ---------------------------------------------------------------------------
// Fallback path (R0): atomic value scatter + finalize. Used if ws too small.
// ---------------------------------------------------------------------------
__global__ void linear1_f32_kernel(const float* __restrict__ x,
                                   const float* __restrict__ W1,
                                   float* __restrict__ h, int n) {
    __shared__ float w[16 * 58];
    for (int idx = threadIdx.x; idx < 16 * 58; idx += blockDim.x)
        w[idx] = W1[idx];
    __syncthreads();
    int i = blockIdx.x * blockDim.x + threadIdx.x;
    if (i >= n) return;
    float xv[58];
    const float* xr = x + (long)i * 58;
#pragma unroll
    for (int k = 0; k < 58; ++k) xv[k] = xr[k];
#pragma unroll
    for (int cq = 0; cq < 4; ++cq) {
        float a[4];
#pragma unroll
        for (int r = 0; r < 4; ++r) {
            int ch = cq * 4 + r;
            float acc = 0.0f;
#pragma unroll
            for (int k = 0; k < 58; ++k) acc += xv[k] * w[ch * 58 + k];
            a[r] = acc;
        }
        ((float4*)(h + (long)i * 16))[cq] = make_float4(a[0], a[1], a[2], a[3]);
    }
}

__global__ void scatter_kernel(const int* __restrict__ ei32,
                               const long long* __restrict__ ei64,
                               const unsigned int* __restrict__ flag,
                               const float* __restrict__ h,
                               float* __restrict__ summed,
                               float* __restrict__ cnt) {
    long e = (long)blockIdx.x * blockDim.x + threadIdx.x;
    if (e >= N_EDGES) return;
    long src, dst;
    if (*flag) { src = (long)ei64[e]; dst = (long)ei64[N_EDGES + e]; }
    else       { src = (long)ei32[e]; dst = (long)ei32[N_EDGES + e]; }
    const float4* hs = (const float4*)(h + src * 16);
    float4 a = hs[0], b = hs[1], c = hs[2], d = hs[3];
    float* o = summed + dst * 16;
    atomicAdd(o + 0,  a.x); atomicAdd(o + 1,  a.y);
    atomicAdd(o + 2,  a.z); atomicAdd(o + 3,  a.w);
    atomicAdd(o + 4,  b.x); atomicAdd(o + 5,  b.y);
    atomicAdd(o + 6,  b.z); atomicAdd(o + 7,  b.w);
    atomicAdd(o + 8,  c.x); atomicAdd(o + 9,  c.y);
    atomicAdd(o + 10, c.z); atomicAdd(o + 11, c.w);
    atomicAdd(o + 12, d.x); atomicAdd(o + 13, d.y);
    atomicAdd(o + 14, d.z); atomicAdd(o + 15, d.w);
    atomicAdd(cnt + dst, 1.0f);
}

__global__ void finalize_kernel(const float* __restrict__ summed,
                                const float* __restrict__ cnt,
                                const float* __restrict__ b1,
                                const float* __restrict__ W2,
                                const float* __restrict__ b2,
                                float* __restrict__ out, int n) {
    int i = blockIdx.x * blockDim.x + threadIdx.x;
    if (i >= n) return;
    const float4* s = (const float4*)(summed + (long)i * 16);
    float4 s0 = s[0], s1 = s[1], s2 = s[2], s3 = s[3];
    float sv[16] = {s0.x, s0.y, s0.z, s0.w, s1.x, s1.y, s1.z, s1.w,
                    s2.x, s2.y, s2.z, s2.w, s3.x, s3.y, s3.z, s3.w};
    float inv = 1.0f / fmaxf(cnt[i], 1.0f);
    float acc = b2[0];
#pragma unroll
    for (int c = 0; c < 16; ++c)
        acc += W2[c] * fmaxf(sv[c] * inv + b1[c], 0.0f);
    out[i] = acc;
}

extern "C" void kernel_launch(void* const* d_in, const int* in_sizes, int n_in,
                              void* d_out, int out_size, void* d_ws, size_t ws_size,
                              hipStream_t stream) {
    const float* x  = (const float*)d_in[0];
    const void*  ei = d_in[1];
    const float* W1 = (const float*)d_in[2];
    const float* b1 = (const float*)d_in[3];
    const float* W2 = (const float*)d_in[4];
    const float* b2 = (const float*)d_in[5];
    float* out = (float*)d_out;

    float* ws = (float*)d_ws;

    // Bucket-path workspace (4B words):
    //   h2     :   800,000 (fp16 h, __half2[N][8] = 3.2 MB)
    //   packed : 3,200,000 u32
    //   bcount : NSCAN (200,192) i32   (scanned in place -> offsets)
    //   bsums  : 512 i32
    //   flag   : 1 u32
    const size_t need_bkt = (size_t)(800000 + 3200000 + NSCAN + 512 + 1) * 4;

    if (ws_size >= need_bkt) {
        __half2*      h2     = (__half2*)ws;
        unsigned int* packed = (unsigned int*)(ws + 800000);
        int*          bcount = (int*)(ws + 800000 + 3200000);
        int*          bsums  = bcount + NSCAN;
        unsigned int* flag   = (unsigned int*)(bsums + 512);

        detect_i64_kernel<<<1, 64, 0, stream>>>((const unsigned int*)ei, flag);

        linear1_kernel<<<(N_NODES + 127) / 128, 128, 0, stream>>>(x, W1, h2, N_NODES);

        hist_kernel<<<EB, 512, 0, stream>>>(
            (const int*)ei, (const long long*)ei, flag, bcount);

        scan1_kernel<<<NB_SCAN, SCAN_BLOCK, 0, stream>>>(bcount, bsums, NSCAN);
        scan2_kernel<<<1, 512, 0, stream>>>(bsums, NB_SCAN);
        scan3_kernel<<<(NSCAN + 255) / 256, 256, 0, stream>>>(bcount, bsums, NSCAN);

        bucket_scatter_kernel<<<EB, 512, 0, stream>>>(
            (const int*)ei, (const long long*)ei, flag, bcount, packed);

        bucket_aggregate_kernel<<<NBKT, 512, 0, stream>>>(
            packed, bcount, h2, b1, W2, b2, out);
    } else {
        // Fallback: R0 atomic-scatter path (13.2 MB workspace).
        float* h      = ws;                  // N_NODES * 16
        float* summed = ws + N_NODES * 16;   // N_NODES * 16
        float* cnt    = ws + N_NODES * 32;   // N_NODES
        unsigned int* flag = (unsigned int*)(ws + N_NODES * 33);

        hipMemsetAsync(summed, 0, (size_t)(N_NODES * 17) * sizeof(float), stream);
        detect_i64_kernel<<<1, 64, 0, stream>>>((const unsigned int*)ei, flag);
        linear1_f32_kernel<<<(N_NODES + 127) / 128, 128, 0, stream>>>(x, W1, h, N_NODES);
        scatter_kernel<<<(N_EDGES + 255) / 256, 256, 0, stream>>>(
            (const int*)ei, (const long long*)ei, flag, h, summed, cnt);
        finalize_kernel<<<(N_NODES + 255) / 256, 256, 0, stream>>>(
            summed, cnt, b1, W2, b2, out, N_NODES);
    }
}

// Round 6
// 411.558 us; speedup vs baseline: 6.7586x; 1.0036x over previous
//
#include <hip/hip_runtime.h>
#include <hip/hip_fp16.h>

#define N_NODES 100000
#define N_EDGES 3200000
#define NBKT 782            // buckets of 128 nodes (dst >> 7)
#define EB 256              // phase-A blocks
#define EPB 12500           // edges per phase-A block (EB*EPB == N_EDGES)
#define SCAN_BLOCK 512
#define NSCAN (NBKT * EB)   // 200192 (bucket-major counts)
#define NB_SCAN ((NSCAN + SCAN_BLOCK - 1) / SCAN_BLOCK)  // 391 (<= 512)

// ---------------------------------------------------------------------------
// Detect int64 vs int32 edge_index (odd 32-bit words all zero => int64).
// ---------------------------------------------------------------------------
__global__ void detect_i64_kernel(const unsigned int* __restrict__ ei,
                                  unsigned int* __restrict__ flag) {
    unsigned int v = 0;
    int lane = threadIdx.x;  // 64 threads
    for (int j = lane; j < 512; j += 64) v |= ei[2 * j + 1];
    unsigned long long any_nonzero = __ballot(v != 0u);
    if (lane == 0) *flag = (any_nonzero == 0ULL) ? 1u : 0u;
}

// ---------------------------------------------------------------------------
// h2[i][c] = fp16( sum_k x[i][k] * W1[c][k] )  -- h stored as __half2[N][8]
// (3.2 MB: fits in every XCD's 4 MiB L2 -> gathers become L2 hits)
// ---------------------------------------------------------------------------
__global__ void linear1_kernel(const float* __restrict__ x,
                               const float* __restrict__ W1,
                               __half2* __restrict__ h2, int n) {
    __shared__ float w[16 * 58];
    for (int idx = threadIdx.x; idx < 16 * 58; idx += blockDim.x)
        w[idx] = W1[idx];
    __syncthreads();

    int i = blockIdx.x * blockDim.x + threadIdx.x;
    if (i >= n) return;

    float xv[58];
    const float* xr = x + (long)i * 58;
#pragma unroll
    for (int k = 0; k < 58; ++k) xv[k] = xr[k];

    __half2 o[8];
#pragma unroll
    for (int q = 0; q < 8; ++q) {
        float a[2];
#pragma unroll
        for (int r = 0; r < 2; ++r) {
            int c = q * 2 + r;
            float acc = 0.0f;
#pragma unroll
            for (int k = 0; k < 58; ++k) acc += xv[k] * w[c * 58 + k];
            a[r] = acc;
        }
        o[q] = __floats2half2_rn(a[0], a[1]);
    }
    // 32B per row, aligned; write as two 16B stores
    float4* dst = (float4*)(h2 + (long)i * 8);
    float4* src = (float4*)o;
    dst[0] = src[0];
    dst[1] = src[1];
}

// ---------------------------------------------------------------------------
// Phase A1: per-(bucket, block) histogram of dst buckets. LDS atomics only.
// bcount is bucket-major: bcount[bucket*EB + block].
// ---------------------------------------------------------------------------
__global__ void hist_kernel(const int* __restrict__ ei32,
                            const long long* __restrict__ ei64,
                            const unsigned int* __restrict__ flag,
                            int* __restrict__ bcount) {
    __shared__ int hist[NBKT];
    for (int i = threadIdx.x; i < NBKT; i += blockDim.x) hist[i] = 0;
    __syncthreads();

    long base = (long)blockIdx.x * EPB;
    bool i64 = (*flag != 0u);
    for (int k = threadIdx.x; k < EPB; k += blockDim.x) {
        long e = base + k;
        int dst = i64 ? (int)ei64[N_EDGES + e] : ei32[N_EDGES + e];
        atomicAdd(&hist[dst >> 7], 1);
    }
    __syncthreads();
    for (int b = threadIdx.x; b < NBKT; b += blockDim.x)
        bcount[(long)b * EB + blockIdx.x] = hist[b];
}

// ---------------------------------------------------------------------------
// In-place exclusive scan of bcount (NSCAN entries), 3 kernels.
// ---------------------------------------------------------------------------
__global__ void scan1_kernel(int* __restrict__ data,
                             int* __restrict__ bsums, int n) {
    __shared__ int tmp[SCAN_BLOCK];
    int i = blockIdx.x * SCAN_BLOCK + threadIdx.x;
    int v = (i < n) ? data[i] : 0;
    tmp[threadIdx.x] = v;
    __syncthreads();
#pragma unroll
    for (int d = 1; d < SCAN_BLOCK; d <<= 1) {
        int t = (threadIdx.x >= d) ? tmp[threadIdx.x - d] : 0;
        __syncthreads();
        tmp[threadIdx.x] += t;
        __syncthreads();
    }
    if (i < n) data[i] = tmp[threadIdx.x] - v;  // exclusive
    if (threadIdx.x == SCAN_BLOCK - 1) bsums[blockIdx.x] = tmp[threadIdx.x];
}

// Parallel LDS exclusive scan of the (<=512) block sums.
__global__ void scan2_kernel(int* __restrict__ bsums, int nb) {
    __shared__ int tmp[512];
    int i = threadIdx.x;
    int v = (i < nb) ? bsums[i] : 0;
    tmp[i] = v;
    __syncthreads();
#pragma unroll
    for (int d = 1; d < 512; d <<= 1) {
        int t = (i >= d) ? tmp[i - d] : 0;
        __syncthreads();
        tmp[i] += t;
        __syncthreads();
    }
    if (i < nb) bsums[i] = tmp[i] - v;  // exclusive
}

__global__ void scan3_kernel(int* __restrict__ data,
                             const int* __restrict__ bsums, int n) {
    int i = blockIdx.x * blockDim.x + threadIdx.x;
    if (i < n) data[i] += bsums[i / SCAN_BLOCK];
}

// ---------------------------------------------------------------------------
// Phase A2: scatter each edge into its bucket region as a packed word:
// (dst & 127) << 17 | src.  Slots come from LDS cursors (per-block regions),
// so global writes are dense runs owned by one block.
// ---------------------------------------------------------------------------
__global__ void bucket_scatter_kernel(const int* __restrict__ ei32,
                                      const long long* __restrict__ ei64,
                                      const unsigned int* __restrict__ flag,
                                      const int* __restrict__ boffs,
                                      unsigned int* __restrict__ packed) {
    __shared__ int cur[NBKT];
    for (int i = threadIdx.x; i < NBKT; i += blockDim.x)
        cur[i] = boffs[(long)i * EB + blockIdx.x];
    __syncthreads();

    long base = (long)blockIdx.x * EPB;
    bool i64 = (*flag != 0u);
    for (int k = threadIdx.x; k < EPB; k += blockDim.x) {
        long e = base + k;
        int src, dst;
        if (i64) { src = (int)ei64[e]; dst = (int)ei64[N_EDGES + e]; }
        else     { src = ei32[e];      dst = ei32[N_EDGES + e]; }
        int p = atomicAdd(&cur[dst >> 7], 1);
        packed[p] = ((unsigned int)(dst & 127) << 17) | (unsigned int)src;
    }
}

// ---------------------------------------------------------------------------
// Phase B: one 512-thread block per 128-node bucket. 8 lanes per edge, each
// lane loads one __half2 (2 channels, 4B) -> 8 edges per wave instruction.
// Unroll-4 keeps 4 gathers in flight. Fused mean+bias+relu+W2-dot epilogue.
// ---------------------------------------------------------------------------
__global__ void __launch_bounds__(512, 4)
bucket_aggregate_kernel(const unsigned int* __restrict__ packed,
                        const int* __restrict__ boffs,
                        const __half2* __restrict__ h2,
                        const float* __restrict__ b1,
                        const float* __restrict__ W2,
                        const float* __restrict__ b2,
                        float* __restrict__ out) {
    __shared__ float sums[128 * 17];   // stride 17: conflict-spread
    __shared__ int cnt[128];

    int b = blockIdx.x;
    for (int i = threadIdx.x; i < 128 * 17; i += blockDim.x) sums[i] = 0.0f;
    if (threadIdx.x < 128) cnt[threadIdx.x] = 0;
    __syncthreads();

    int start = boffs[(long)b * EB];
    int end = (b + 1 < NBKT) ? boffs[(long)(b + 1) * EB] : N_EDGES;

    int c = threadIdx.x & 7;                // channel-pair index (0..7)
    int stride = (int)(blockDim.x >> 3);    // 64 edge-groups
    int e = start + (int)(threadIdx.x >> 3);

    // unroll-4: four independent gathers in flight per thread
    for (; e + 3 * stride < end; e += 4 * stride) {
        unsigned int v0 = packed[e];
        unsigned int v1 = packed[e + stride];
        unsigned int v2 = packed[e + 2 * stride];
        unsigned int v3 = packed[e + 3 * stride];
        int s0 = (int)(v0 & 0x1FFFFu), l0 = (int)(v0 >> 17);
        int s1 = (int)(v1 & 0x1FFFFu), l1 = (int)(v1 >> 17);
        int s2 = (int)(v2 & 0x1FFFFu), l2 = (int)(v2 >> 17);
        int s3 = (int)(v3 & 0x1FFFFu), l3 = (int)(v3 >> 17);
        float2 f0 = __half22float2(h2[(long)s0 * 8 + c]);
        float2 f1 = __half22float2(h2[(long)s1 * 8 + c]);
        float2 f2 = __half22float2(h2[(long)s2 * 8 + c]);
        float2 f3 = __half22float2(h2[(long)s3 * 8 + c]);
        atomicAdd(&sums[l0 * 17 + 2 * c],     f0.x);
        atomicAdd(&sums[l0 * 17 + 2 * c + 1], f0.y);
        atomicAdd(&sums[l1 * 17 + 2 * c],     f1.x);
        atomicAdd(&sums[l1 * 17 + 2 * c + 1], f1.y);
        atomicAdd(&sums[l2 * 17 + 2 * c],     f2.x);
        atomicAdd(&sums[l2 * 17 + 2 * c + 1], f2.y);
        atomicAdd(&sums[l3 * 17 + 2 * c],     f3.x);
        atomicAdd(&sums[l3 * 17 + 2 * c + 1], f3.y);
        if (c == 0) {
            atomicAdd(&cnt[l0], 1); atomicAdd(&cnt[l1], 1);
            atomicAdd(&cnt[l2], 1); atomicAdd(&cnt[l3], 1);
        }
    }
    for (; e < end; e += stride) {
        unsigned int v = packed[e];
        int s = (int)(v & 0x1FFFFu), ld = (int)(v >> 17);
        float2 f = __half22float2(h2[(long)s * 8 + c]);
        atomicAdd(&sums[ld * 17 + 2 * c],     f.x);
        atomicAdd(&sums[ld * 17 + 2 * c + 1], f.y);
        if (c == 0) atomicAdd(&cnt[ld], 1);
    }
    __syncthreads();

    int t = threadIdx.x;                  // first 128 threads = 128 nodes
    int g = b * 128 + t;
    if (t < 128 && g < N_NODES) {
        float inv = 1.0f / fmaxf((float)cnt[t], 1.0f);
        float acc = b2[0];
#pragma unroll
        for (int ch = 0; ch < 16; ++ch)
            acc += W2[ch] * fmaxf(sums[t * 17 + ch] * inv + b1[ch], 0.0f);
        out[g] = acc;
    }
}

// ---------------------------------------------------------------------------
// Fallback path (R0): atomic value scatter + finalize. Used if ws too small.
// ---------------------------------------------------------------------------
__global__ void linear1_f32_kernel(const float* __restrict__ x,
                                   const float* __restrict__ W1,
                                   float* __restrict__ h, int n) {
    __shared__ float w[16 * 58];
    for (int idx = threadIdx.x; idx < 16 * 58; idx += blockDim.x)
        w[idx] = W1[idx];
    __syncthreads();
    int i = blockIdx.x * blockDim.x + threadIdx.x;
    if (i >= n) return;
    float xv[58];
    const float* xr = x + (long)i * 58;
#pragma unroll
    for (int k = 0; k < 58; ++k) xv[k] = xr[k];
#pragma unroll
    for (int cq = 0; cq < 4; ++cq) {
        float a[4];
#pragma unroll
        for (int r = 0; r < 4; ++r) {
            int ch = cq * 4 + r;
            float acc = 0.0f;
#pragma unroll
            for (int k = 0; k < 58; ++k) acc += xv[k] * w[ch * 58 + k];
            a[r] = acc;
        }
        ((float4*)(h + (long)i * 16))[cq] = make_float4(a[0], a[1], a[2], a[3]);
    }
}

__global__ void scatter_kernel(const int* __restrict__ ei32,
                               const long long* __restrict__ ei64,
                               const unsigned int* __restrict__ flag,
                               const float* __restrict__ h,
                               float* __restrict__ summed,
                               float* __restrict__ cnt) {
    long e = (long)blockIdx.x * blockDim.x + threadIdx.x;
    if (e >= N_EDGES) return;
    long src, dst;
    if (*flag) { src = (long)ei64[e]; dst = (long)ei64[N_EDGES + e]; }
    else       { src = (long)ei32[e]; dst = (long)ei32[N_EDGES + e]; }
    const float4* hs = (const float4*)(h + src * 16);
    float4 a = hs[0], b = hs[1], c = hs[2], d = hs[3];
    float* o = summed + dst * 16;
    atomicAdd(o + 0,  a.x); atomicAdd(o + 1,  a.y);
    atomicAdd(o + 2,  a.z); atomicAdd(o + 3,  a.w);
    atomicAdd(o + 4,  b.x); atomicAdd(o + 5,  b.y);
    atomicAdd(o + 6,  b.z); atomicAdd(o + 7,  b.w);
    atomicAdd(o + 8,  c.x); atomicAdd(o + 9,  c.y);
    atomicAdd(o + 10, c.z); atomicAdd(o + 11, c.w);
    atomicAdd(o + 12, d.x); atomicAdd(o + 13, d.y);
    atomicAdd(o + 14, d.z); atomicAdd(o + 15, d.w);
    atomicAdd(cnt + dst, 1.0f);
}

__global__ void finalize_kernel(const float* __restrict__ summed,
                                const float* __restrict__ cnt,
                                const float* __restrict__ b1,
                                const float* __restrict__ W2,
                                const float* __restrict__ b2,
                                float* __restrict__ out, int n) {
    int i = blockIdx.x * blockDim.x + threadIdx.x;
    if (i >= n) return;
    const float4* s = (const float4*)(summed + (long)i * 16);
    float4 s0 = s[0], s1 = s[1], s2 = s[2], s3 = s[3];
    float sv[16] = {s0.x, s0.y, s0.z, s0.w, s1.x, s1.y, s1.z, s1.w,
                    s2.x, s2.y, s2.z, s2.w, s3.x, s3.y, s3.z, s3.w};
    float inv = 1.0f / fmaxf(cnt[i], 1.0f);
    float acc = b2[0];
#pragma unroll
    for (int c = 0; c < 16; ++c)
        acc += W2[c] * fmaxf(sv[c] * inv + b1[c], 0.0f);
    out[i] = acc;
}

extern "C" void kernel_launch(void* const* d_in, const int* in_sizes, int n_in,
                              void* d_out, int out_size, void* d_ws, size_t ws_size,
                              hipStream_t stream) {
    const float* x  = (const float*)d_in[0];
    const void*  ei = d_in[1];
    const float* W1 = (const float*)d_in[2];
    const float* b1 = (const float*)d_in[3];
    const float* W2 = (const float*)d_in[4];
    const float* b2 = (const float*)d_in[5];
    float* out = (float*)d_out;

    float* ws = (float*)d_ws;

    // Bucket-path workspace (4B words):
    //   h2     :   800,000 (fp16 h, __half2[N][8] = 3.2 MB)
    //   packed : 3,200,000 u32
    //   bcount : NSCAN (200,192) i32   (scanned in place -> offsets)
    //   bsums  : 512 i32
    //   flag   : 1 u32
    const size_t need_bkt = (size_t)(800000 + 3200000 + NSCAN + 512 + 1) * 4;

    if (ws_size >= need_bkt) {
        __half2*      h2     = (__half2*)ws;
        unsigned int* packed = (unsigned int*)(ws + 800000);
        int*          bcount = (int*)(ws + 800000 + 3200000);
        int*          bsums  = bcount + NSCAN;
        unsigned int* flag   = (unsigned int*)(bsums + 512);

        detect_i64_kernel<<<1, 64, 0, stream>>>((const unsigned int*)ei, flag);

        linear1_kernel<<<(N_NODES + 127) / 128, 128, 0, stream>>>(x, W1, h2, N_NODES);

        hist_kernel<<<EB, 512, 0, stream>>>(
            (const int*)ei, (const long long*)ei, flag, bcount);

        scan1_kernel<<<NB_SCAN, SCAN_BLOCK, 0, stream>>>(bcount, bsums, NSCAN);
        scan2_kernel<<<1, 512, 0, stream>>>(bsums, NB_SCAN);
        scan3_kernel<<<(NSCAN + 255) / 256, 256, 0, stream>>>(bcount, bsums, NSCAN);

        bucket_scatter_kernel<<<EB, 512, 0, stream>>>(
            (const int*)ei, (const long long*)ei, flag, bcount, packed);

        bucket_aggregate_kernel<<<NBKT, 512, 0, stream>>>(
            packed, bcount, h2, b1, W2, b2, out);
    } else {
        // Fallback: R0 atomic-scatter path (13.2 MB workspace).
        float* h      = ws;                  // N_NODES * 16
        float* summed = ws + N_NODES * 16;   // N_NODES * 16
        float* cnt    = ws + N_NODES * 32;   // N_NODES
        unsigned int* flag = (unsigned int*)(ws + N_NODES * 33);

        hipMemsetAsync(summed, 0, (size_t)(N_NODES * 17) * sizeof(float), stream);
        detect_i64_kernel<<<1, 64, 0, stream>>>((const unsigned int*)ei, flag);
        linear1_f32_kernel<<<(N_NODES + 127) / 128, 128, 0, stream>>>(x, W1, h, N_NODES);
        scatter_kernel<<<(N_EDGES + 255) / 256, 256, 0, stream>>>(
            (const int*)ei, (const long long*)ei, flag, h, summed, cnt);
        finalize_kernel<<<(N_NODES + 255) / 256, 256, 0, stream>>>(
            summed, cnt, b1, W2, b2, out, N_NODES);
    }
}

// Round 8
// 119.191 us; speedup vs baseline: 23.3369x; 3.4529x over previous
//
#include <hip/hip_runtime.h>
#include <hip/hip_fp16.h>

#define N_NODES 100000
#define N_EDGES 3200000
#define NBKT 782            // buckets of 128 nodes (dst >> 7)
#define EB 256              // phase-A blocks
#define EPB 12500           // edges per phase-A block (EB*EPB == N_EDGES)
#define SCAN_BLOCK 512
#define NSCAN (NBKT * EB)   // 200192 (bucket-major counts)
#define NB_SCAN ((NSCAN + SCAN_BLOCK - 1) / SCAN_BLOCK)  // 391 (<= 512)
#define SORT_CAP 5120       // per-bucket sorted-edge LDS capacity (20 KB)

// ---------------------------------------------------------------------------
// Detect int64 vs int32 edge_index (odd 32-bit words all zero => int64).
// ---------------------------------------------------------------------------
__global__ void detect_i64_kernel(const unsigned int* __restrict__ ei,
                                  unsigned int* __restrict__ flag) {
    unsigned int v = 0;
    int lane = threadIdx.x;  // 64 threads
    for (int j = lane; j < 512; j += 64) v |= ei[2 * j + 1];
    unsigned long long any_nonzero = __ballot(v != 0u);
    if (lane == 0) *flag = (any_nonzero == 0ULL) ? 1u : 0u;
}

// ---------------------------------------------------------------------------
// h2[i][c] = fp16( sum_k x[i][k] * W1[c][k] )  -- h stored as __half2[N][8]
// ---------------------------------------------------------------------------
__global__ void linear1_kernel(const float* __restrict__ x,
                               const float* __restrict__ W1,
                               __half2* __restrict__ h2, int n) {
    __shared__ float w[16 * 58];
    for (int idx = threadIdx.x; idx < 16 * 58; idx += blockDim.x)
        w[idx] = W1[idx];
    __syncthreads();

    int i = blockIdx.x * blockDim.x + threadIdx.x;
    if (i >= n) return;

    float xv[58];
    const float* xr = x + (long)i * 58;
#pragma unroll
    for (int k = 0; k < 58; ++k) xv[k] = xr[k];

    __half2 o[8];
#pragma unroll
    for (int q = 0; q < 8; ++q) {
        float a[2];
#pragma unroll
        for (int r = 0; r < 2; ++r) {
            int c = q * 2 + r;
            float acc = 0.0f;
#pragma unroll
            for (int k = 0; k < 58; ++k) acc += xv[k] * w[c * 58 + k];
            a[r] = acc;
        }
        o[q] = __floats2half2_rn(a[0], a[1]);
    }
    float4* dst = (float4*)(h2 + (long)i * 8);
    float4* src = (float4*)o;
    dst[0] = src[0];
    dst[1] = src[1];
}

// ---------------------------------------------------------------------------
// Phase A1: per-(bucket, block) histogram of dst buckets.
// ---------------------------------------------------------------------------
__global__ void hist_kernel(const int* __restrict__ ei32,
                            const long long* __restrict__ ei64,
                            const unsigned int* __restrict__ flag,
                            int* __restrict__ bcount) {
    __shared__ int hist[NBKT];
    for (int i = threadIdx.x; i < NBKT; i += blockDim.x) hist[i] = 0;
    __syncthreads();

    long base = (long)blockIdx.x * EPB;
    bool i64 = (*flag != 0u);
    for (int k = threadIdx.x; k < EPB; k += blockDim.x) {
        long e = base + k;
        int dst = i64 ? (int)ei64[N_EDGES + e] : ei32[N_EDGES + e];
        atomicAdd(&hist[dst >> 7], 1);
    }
    __syncthreads();
    for (int b = threadIdx.x; b < NBKT; b += blockDim.x)
        bcount[(long)b * EB + blockIdx.x] = hist[b];
}

// ---------------------------------------------------------------------------
// In-place exclusive scan of bcount (NSCAN entries), 3 kernels.
// ---------------------------------------------------------------------------
__global__ void scan1_kernel(int* __restrict__ data,
                             int* __restrict__ bsums, int n) {
    __shared__ int tmp[SCAN_BLOCK];
    int i = blockIdx.x * SCAN_BLOCK + threadIdx.x;
    int v = (i < n) ? data[i] : 0;
    tmp[threadIdx.x] = v;
    __syncthreads();
#pragma unroll
    for (int d = 1; d < SCAN_BLOCK; d <<= 1) {
        int t = (threadIdx.x >= d) ? tmp[threadIdx.x - d] : 0;
        __syncthreads();
        tmp[threadIdx.x] += t;
        __syncthreads();
    }
    if (i < n) data[i] = tmp[threadIdx.x] - v;  // exclusive
    if (threadIdx.x == SCAN_BLOCK - 1) bsums[blockIdx.x] = tmp[threadIdx.x];
}

__global__ void scan2_kernel(int* __restrict__ bsums, int nb) {
    __shared__ int tmp[512];
    int i = threadIdx.x;
    int v = (i < nb) ? bsums[i] : 0;
    tmp[i] = v;
    __syncthreads();
#pragma unroll
    for (int d = 1; d < 512; d <<= 1) {
        int t = (i >= d) ? tmp[i - d] : 0;
        __syncthreads();
        tmp[i] += t;
        __syncthreads();
    }
    if (i < nb) bsums[i] = tmp[i] - v;  // exclusive
}

__global__ void scan3_kernel(int* __restrict__ data,
                             const int* __restrict__ bsums, int n) {
    int i = blockIdx.x * blockDim.x + threadIdx.x;
    if (i < n) data[i] += bsums[i / SCAN_BLOCK];
}

// ---------------------------------------------------------------------------
// Phase A2: scatter each edge into its bucket region as a packed word:
// (dst & 127) << 17 | src.
// ---------------------------------------------------------------------------
__global__ void bucket_scatter_kernel(const int* __restrict__ ei32,
                                      const long long* __restrict__ ei64,
                                      const unsigned int* __restrict__ flag,
                                      const int* __restrict__ boffs,
                                      unsigned int* __restrict__ packed) {
    __shared__ int cur[NBKT];
    for (int i = threadIdx.x; i < NBKT; i += blockDim.x)
        cur[i] = boffs[(long)i * EB + blockIdx.x];
    __syncthreads();

    long base = (long)blockIdx.x * EPB;
    bool i64 = (*flag != 0u);
    for (int k = threadIdx.x; k < EPB; k += blockDim.x) {
        long e = base + k;
        int src, dst;
        if (i64) { src = (int)ei64[e]; dst = (int)ei64[N_EDGES + e]; }
        else     { src = ei32[e];      dst = ei32[N_EDGES + e]; }
        int p = atomicAdd(&cur[dst >> 7], 1);
        packed[p] = ((unsigned int)(dst & 127) << 17) | (unsigned int)src;
    }
}

// ---------------------------------------------------------------------------
// Phase B1: per-bucket counting sort in LDS, written BACK TO GLOBAL.
// The node-sorted src list replaces packed[start..end) in place; per-node
// (deg, start) meta goes to global. The kernel boundary between sort and
// gather guarantees global visibility of everything the consumer reads.
// Buckets with m > SORT_CAP (>=16 sigma; effectively never) are left
// unsorted and flagged via bsort[b]=0; gather handles them by filter-scan.
// ---------------------------------------------------------------------------
__global__ void __launch_bounds__(512, 4)
sort_kernel(unsigned int* __restrict__ packed,
            const int* __restrict__ boffs,
            int* __restrict__ ndeg,
            int* __restrict__ nstart,
            int* __restrict__ bsort) {
    __shared__ unsigned int sorted[SORT_CAP];  // 20 KB
    __shared__ int hist[128];
    __shared__ int starts[128];
    __shared__ int curs[128];
    __shared__ int tmp[512];

    int b = blockIdx.x;
    int tid = threadIdx.x;
    int start = boffs[(long)b * EB];
    int end = (b + 1 < NBKT) ? boffs[(long)(b + 1) * EB] : N_EDGES;
    int m = end - start;

    if (tid < 128) hist[tid] = 0;
    __syncthreads();

    // 1. per-node histogram
    for (int k = tid; k < m; k += 512)
        atomicAdd(&hist[(int)(packed[start + k] >> 17)], 1);
    __syncthreads();

    // 2. exclusive scan (scan1's proven 512-wide pattern; entries >=128 = 0)
    int v = (tid < 128) ? hist[tid] : 0;
    tmp[tid] = v;
    __syncthreads();
#pragma unroll
    for (int d = 1; d < 512; d <<= 1) {
        int t = (tid >= d) ? tmp[tid - d] : 0;
        __syncthreads();
        tmp[tid] += t;
        __syncthreads();
    }
    if (tid < 128) {
        int s = tmp[tid] - v;
        starts[tid] = s;
        curs[tid] = s;
    }
    __syncthreads();

    bool fast = (m <= SORT_CAP);   // uniform across the block
    if (fast) {
        // 3. cursor-scatter src into sorted[]
        for (int k = tid; k < m; k += 512) {
            unsigned int w = packed[start + k];
            int l = (int)(w >> 17);
            int p = atomicAdd(&curs[l], 1);
            sorted[p] = w & 0x1FFFFu;
        }
        __threadfence_block();
        __syncthreads();
        // 4. write node-sorted src list back to global (dense, coalesced)
        for (int k = tid; k < m; k += 512)
            packed[start + k] = sorted[k];
    }

    // 5. per-node meta
    if (tid < 128) {
        int g = b * 128 + tid;
        if (g < N_NODES) {
            ndeg[g] = hist[tid];
            nstart[g] = start + starts[tid];
        }
    }
    if (tid == 0) bsort[b] = fast ? 1 : 0;
}

// ---------------------------------------------------------------------------
// Phase B2: barrier-free, LDS-free gather. 8 lanes per node, each lane owns
// 2 channels; serial unroll-2 over the node's contiguous src list; fused
// mean + bias + relu + W2-dot + b2; shfl-reduce; write out.
// 8-lane groups are g-uniform, so the early return never splits a group.
// ---------------------------------------------------------------------------
__global__ void __launch_bounds__(512, 8)
gather_kernel(const unsigned int* __restrict__ packed,
              const int* __restrict__ ndeg,
              const int* __restrict__ nstart,
              const int* __restrict__ bsort,
              const int* __restrict__ boffs,
              const __half2* __restrict__ h2,
              const float* __restrict__ b1,
              const float* __restrict__ W2,
              const float* __restrict__ b2,
              float* __restrict__ out) {
    int bb = blockIdx.x;                         // 2*NBKT blocks
    int b = bb >> 1;
    int l = (bb & 1) * 64 + (threadIdx.x >> 3);  // node-in-bucket 0..127
    int c = threadIdx.x & 7;                     // channel pair 0..7
    int g = b * 128 + l;
    if (g >= N_NODES) return;                    // group-uniform; no barriers

    int deg = ndeg[g];
    float2 acc0 = {0.0f, 0.0f}, acc1 = {0.0f, 0.0f};

    if (bsort[b]) {
        int p = nstart[g], pend = p + deg;
        for (; p + 1 < pend; p += 2) {
            int sA = (int)packed[p];
            int sB = (int)packed[p + 1];
            float2 fA = __half22float2(h2[(long)sA * 8 + c]);
            float2 fB = __half22float2(h2[(long)sB * 8 + c]);
            acc0.x += fA.x; acc0.y += fA.y;
            acc1.x += fB.x; acc1.y += fB.y;
        }
        if (p < pend) {
            float2 f = __half22float2(h2[(long)packed[p] * 8 + c]);
            acc0.x += f.x; acc0.y += f.y;
        }
    } else {
        // never-expected universal fallback: filter-scan the whole bucket
        int bs = boffs[(long)b * EB];
        int be = (b + 1 < NBKT) ? boffs[(long)(b + 1) * EB] : N_EDGES;
        for (int p = bs; p < be; ++p) {
            unsigned int w = packed[p];
            if ((int)(w >> 17) == l) {
                float2 f = __half22float2(h2[(long)(w & 0x1FFFFu) * 8 + c]);
                acc0.x += f.x; acc0.y += f.y;
            }
        }
    }

    float inv = 1.0f / fmaxf((float)deg, 1.0f);
    float sx = acc0.x + acc1.x, sy = acc0.y + acc1.y;
    float v = fmaxf(sx * inv + b1[2 * c], 0.0f)     * W2[2 * c]
            + fmaxf(sy * inv + b1[2 * c + 1], 0.0f) * W2[2 * c + 1];
    v += __shfl_xor(v, 1);
    v += __shfl_xor(v, 2);
    v += __shfl_xor(v, 4);
    if (c == 0) out[g] = v + b2[0];
}

// ---------------------------------------------------------------------------
// Fallback path (R0): atomic value scatter + finalize. Used if ws too small.
// ---------------------------------------------------------------------------
__global__ void linear1_f32_kernel(const float* __restrict__ x,
                                   const float* __restrict__ W1,
                                   float* __restrict__ h, int n) {
    __shared__ float w[16 * 58];
    for (int idx = threadIdx.x; idx < 16 * 58; idx += blockDim.x)
        w[idx] = W1[idx];
    __syncthreads();
    int i = blockIdx.x * blockDim.x + threadIdx.x;
    if (i >= n) return;
    float xv[58];
    const float* xr = x + (long)i * 58;
#pragma unroll
    for (int k = 0; k < 58; ++k) xv[k] = xr[k];
#pragma unroll
    for (int cq = 0; cq < 4; ++cq) {
        float a[4];
#pragma unroll
        for (int r = 0; r < 4; ++r) {
            int ch = cq * 4 + r;
            float acc = 0.0f;
#pragma unroll
            for (int k = 0; k < 58; ++k) acc += xv[k] * w[ch * 58 + k];
            a[r] = acc;
        }
        ((float4*)(h + (long)i * 16))[cq] = make_float4(a[0], a[1], a[2], a[3]);
    }
}

__global__ void scatter_kernel(const int* __restrict__ ei32,
                               const long long* __restrict__ ei64,
                               const unsigned int* __restrict__ flag,
                               const float* __restrict__ h,
                               float* __restrict__ summed,
                               float* __restrict__ cnt) {
    long e = (long)blockIdx.x * blockDim.x + threadIdx.x;
    if (e >= N_EDGES) return;
    long src, dst;
    if (*flag) { src = (long)ei64[e]; dst = (long)ei64[N_EDGES + e]; }
    else       { src = (long)ei32[e]; dst = (long)ei32[N_EDGES + e]; }
    const float4* hs = (const float4*)(h + src * 16);
    float4 a = hs[0], b = hs[1], c = hs[2], d = hs[3];
    float* o = summed + dst * 16;
    atomicAdd(o + 0,  a.x); atomicAdd(o + 1,  a.y);
    atomicAdd(o + 2,  a.z); atomicAdd(o + 3,  a.w);
    atomicAdd(o + 4,  b.x); atomicAdd(o + 5,  b.y);
    atomicAdd(o + 6,  b.z); atomicAdd(o + 7,  b.w);
    atomicAdd(o + 8,  c.x); atomicAdd(o + 9,  c.y);
    atomicAdd(o + 10, c.z); atomicAdd(o + 11, c.w);
    atomicAdd(o + 12, d.x); atomicAdd(o + 13, d.y);
    atomicAdd(o + 14, d.z); atomicAdd(o + 15, d.w);
    atomicAdd(cnt + dst, 1.0f);
}

__global__ void finalize_kernel(const float* __restrict__ summed,
                                const float* __restrict__ cnt,
                                const float* __restrict__ b1,
                                const float* __restrict__ W2,
                                const float* __restrict__ b2,
                                float* __restrict__ out, int n) {
    int i = blockIdx.x * blockDim.x + threadIdx.x;
    if (i >= n) return;
    const float4* s = (const float4*)(summed + (long)i * 16);
    float4 s0 = s[0], s1 = s[1], s2 = s[2], s3 = s[3];
    float sv[16] = {s0.x, s0.y, s0.z, s0.w, s1.x, s1.y, s1.z, s1.w,
                    s2.x, s2.y, s2.z, s2.w, s3.x, s3.y, s3.z, s3.w};
    float inv = 1.0f / fmaxf(cnt[i], 1.0f);
    float acc = b2[0];
#pragma unroll
    for (int c = 0; c < 16; ++c)
        acc += W2[c] * fmaxf(sv[c] * inv + b1[c], 0.0f);
    out[i] = acc;
}

extern "C" void kernel_launch(void* const* d_in, const int* in_sizes, int n_in,
                              void* d_out, int out_size, void* d_ws, size_t ws_size,
                              hipStream_t stream) {
    const float* x  = (const float*)d_in[0];
    const void*  ei = d_in[1];
    const float* W1 = (const float*)d_in[2];
    const float* b1 = (const float*)d_in[3];
    const float* W2 = (const float*)d_in[4];
    const float* b2 = (const float*)d_in[5];
    float* out = (float*)d_out;

    float* ws = (float*)d_ws;

    // Bucket-path workspace (4B words):
    //   h2     :   800,000  (fp16 h, __half2[N][8] = 3.2 MB)
    //   packed : 3,200,000  u32 (edge words; node-sorted in place by sort)
    //   bcount :   NSCAN    i32 (scanned in place -> offsets)
    //   bsums  :       512  i32
    //   flag   :         1  u32
    //   ndeg   :   100,000  i32
    //   nstart :   100,000  i32
    //   bsort  :       782  i32
    const size_t need_bkt =
        (size_t)(800000 + 3200000 + NSCAN + 512 + 1 + 100000 + 100000 + NBKT) * 4;

    if (ws_size >= need_bkt) {
        __half2*      h2     = (__half2*)ws;
        unsigned int* packed = (unsigned int*)(ws + 800000);
        int*          bcount = (int*)(ws + 800000 + 3200000);
        int*          bsums  = bcount + NSCAN;
        unsigned int* flag   = (unsigned int*)(bsums + 512);
        int*          ndeg   = (int*)(flag + 1);
        int*          nstart = ndeg + 100000;
        int*          bsort  = nstart + 100000;

        detect_i64_kernel<<<1, 64, 0, stream>>>((const unsigned int*)ei, flag);

        linear1_kernel<<<(N_NODES + 127) / 128, 128, 0, stream>>>(x, W1, h2, N_NODES);

        hist_kernel<<<EB, 512, 0, stream>>>(
            (const int*)ei, (const long long*)ei, flag, bcount);

        scan1_kernel<<<NB_SCAN, SCAN_BLOCK, 0, stream>>>(bcount, bsums, NSCAN);
        scan2_kernel<<<1, 512, 0, stream>>>(bsums, NB_SCAN);
        scan3_kernel<<<(NSCAN + 255) / 256, 256, 0, stream>>>(bcount, bsums, NSCAN);

        bucket_scatter_kernel<<<EB, 512, 0, stream>>>(
            (const int*)ei, (const long long*)ei, flag, bcount, packed);

        sort_kernel<<<NBKT, 512, 0, stream>>>(packed, bcount, ndeg, nstart, bsort);

        gather_kernel<<<NBKT * 2, 512, 0, stream>>>(
            packed, ndeg, nstart, bsort, bcount, h2, b1, W2, b2, out);
    } else {
        // Fallback: R0 atomic-scatter path (13.2 MB workspace).
        float* h      = ws;                  // N_NODES * 16
        float* summed = ws + N_NODES * 16;   // N_NODES * 16
        float* cnt    = ws + N_NODES * 32;   // N_NODES
        unsigned int* flag = (unsigned int*)(ws + N_NODES * 33);

        hipMemsetAsync(summed, 0, (size_t)(N_NODES * 17) * sizeof(float), stream);
        detect_i64_kernel<<<1, 64, 0, stream>>>((const unsigned int*)ei, flag);
        linear1_f32_kernel<<<(N_NODES + 127) / 128, 128, 0, stream>>>(x, W1, h, N_NODES);
        scatter_kernel<<<(N_EDGES + 255) / 256, 256, 0, stream>>>(
            (const int*)ei, (const long long*)ei, flag, h, summed, cnt);
        finalize_kernel<<<(N_NODES + 255) / 256, 256, 0, stream>>>(
            summed, cnt, b1, W2, b2, out, N_NODES);
    }
}

// Round 9
// 118.672 us; speedup vs baseline: 23.4390x; 1.0044x over previous
//
#include <hip/hip_runtime.h>
#include <hip/hip_fp16.h>

#define N_NODES 100000
#define N_EDGES 3200000
#define NBKT 782            // buckets of 128 nodes (dst >> 7)
#define EB 256              // phase-A blocks
#define EPB 12500           // edges per phase-A block (EB*EPB == N_EDGES)
#define SCAN_BLOCK 512
#define NSCAN (NBKT * EB)   // 200192 (bucket-major counts)
#define NB_SCAN ((NSCAN + SCAN_BLOCK - 1) / SCAN_BLOCK)  // 391 (<= 512)
#define SORT_CAP 5120       // per-bucket sorted-edge LDS capacity (20 KB)

// ---------------------------------------------------------------------------
// Detect int64 vs int32 edge_index (odd 32-bit words all zero => int64).
// ---------------------------------------------------------------------------
__global__ void detect_i64_kernel(const unsigned int* __restrict__ ei,
                                  unsigned int* __restrict__ flag) {
    unsigned int v = 0;
    int lane = threadIdx.x;  // 64 threads
    for (int j = lane; j < 512; j += 64) v |= ei[2 * j + 1];
    unsigned long long any_nonzero = __ballot(v != 0u);
    if (lane == 0) *flag = (any_nonzero == 0ULL) ? 1u : 0u;
}

// ---------------------------------------------------------------------------
// h2[i][c] = fp16( sum_k x[i][k] * W1[c][k] )  -- h stored as __half2[N][8]
// ---------------------------------------------------------------------------
__global__ void linear1_kernel(const float* __restrict__ x,
                               const float* __restrict__ W1,
                               __half2* __restrict__ h2, int n) {
    __shared__ float w[16 * 58];
    for (int idx = threadIdx.x; idx < 16 * 58; idx += blockDim.x)
        w[idx] = W1[idx];
    __syncthreads();

    int i = blockIdx.x * blockDim.x + threadIdx.x;
    if (i >= n) return;

    float xv[58];
    const float* xr = x + (long)i * 58;
#pragma unroll
    for (int k = 0; k < 58; ++k) xv[k] = xr[k];

    __half2 o[8];
#pragma unroll
    for (int q = 0; q < 8; ++q) {
        float a[2];
#pragma unroll
        for (int r = 0; r < 2; ++r) {
            int c = q * 2 + r;
            float acc = 0.0f;
#pragma unroll
            for (int k = 0; k < 58; ++k) acc += xv[k] * w[c * 58 + k];
            a[r] = acc;
        }
        o[q] = __floats2half2_rn(a[0], a[1]);
    }
    float4* dst = (float4*)(h2 + (long)i * 8);
    float4* src = (float4*)o;
    dst[0] = src[0];
    dst[1] = src[1];
}

// ---------------------------------------------------------------------------
// Phase A1: per-(bucket, block) histogram of dst buckets.
// ---------------------------------------------------------------------------
__global__ void hist_kernel(const int* __restrict__ ei32,
                            const long long* __restrict__ ei64,
                            const unsigned int* __restrict__ flag,
                            int* __restrict__ bcount) {
    __shared__ int hist[NBKT];
    for (int i = threadIdx.x; i < NBKT; i += blockDim.x) hist[i] = 0;
    __syncthreads();

    long base = (long)blockIdx.x * EPB;
    bool i64 = (*flag != 0u);
    for (int k = threadIdx.x; k < EPB; k += blockDim.x) {
        long e = base + k;
        int dst = i64 ? (int)ei64[N_EDGES + e] : ei32[N_EDGES + e];
        atomicAdd(&hist[dst >> 7], 1);
    }
    __syncthreads();
    for (int b = threadIdx.x; b < NBKT; b += blockDim.x)
        bcount[(long)b * EB + blockIdx.x] = hist[b];
}

// ---------------------------------------------------------------------------
// In-place exclusive scan of bcount (NSCAN entries), 3 kernels.
// ---------------------------------------------------------------------------
__global__ void scan1_kernel(int* __restrict__ data,
                             int* __restrict__ bsums, int n) {
    __shared__ int tmp[SCAN_BLOCK];
    int i = blockIdx.x * SCAN_BLOCK + threadIdx.x;
    int v = (i < n) ? data[i] : 0;
    tmp[threadIdx.x] = v;
    __syncthreads();
#pragma unroll
    for (int d = 1; d < SCAN_BLOCK; d <<= 1) {
        int t = (threadIdx.x >= d) ? tmp[threadIdx.x - d] : 0;
        __syncthreads();
        tmp[threadIdx.x] += t;
        __syncthreads();
    }
    if (i < n) data[i] = tmp[threadIdx.x] - v;  // exclusive
    if (threadIdx.x == SCAN_BLOCK - 1) bsums[blockIdx.x] = tmp[threadIdx.x];
}

__global__ void scan2_kernel(int* __restrict__ bsums, int nb) {
    __shared__ int tmp[512];
    int i = threadIdx.x;
    int v = (i < nb) ? bsums[i] : 0;
    tmp[i] = v;
    __syncthreads();
#pragma unroll
    for (int d = 1; d < 512; d <<= 1) {
        int t = (i >= d) ? tmp[i - d] : 0;
        __syncthreads();
        tmp[i] += t;
        __syncthreads();
    }
    if (i < nb) bsums[i] = tmp[i] - v;  // exclusive
}

__global__ void scan3_kernel(int* __restrict__ data,
                             const int* __restrict__ bsums, int n) {
    int i = blockIdx.x * blockDim.x + threadIdx.x;
    if (i < n) data[i] += bsums[i / SCAN_BLOCK];
}

// ---------------------------------------------------------------------------
// Phase A2: scatter each edge into its bucket region as a packed word:
// (dst & 127) << 17 | src.
// ---------------------------------------------------------------------------
__global__ void bucket_scatter_kernel(const int* __restrict__ ei32,
                                      const long long* __restrict__ ei64,
                                      const unsigned int* __restrict__ flag,
                                      const int* __restrict__ boffs,
                                      unsigned int* __restrict__ packed) {
    __shared__ int cur[NBKT];
    for (int i = threadIdx.x; i < NBKT; i += blockDim.x)
        cur[i] = boffs[(long)i * EB + blockIdx.x];
    __syncthreads();

    long base = (long)blockIdx.x * EPB;
    bool i64 = (*flag != 0u);
    for (int k = threadIdx.x; k < EPB; k += blockDim.x) {
        long e = base + k;
        int src, dst;
        if (i64) { src = (int)ei64[e]; dst = (int)ei64[N_EDGES + e]; }
        else     { src = ei32[e];      dst = ei32[N_EDGES + e]; }
        int p = atomicAdd(&cur[dst >> 7], 1);
        packed[p] = ((unsigned int)(dst & 127) << 17) | (unsigned int)src;
    }
}

// ---------------------------------------------------------------------------
// Phase B1: per-bucket counting sort in LDS, written BACK TO GLOBAL.
// The node-sorted src list replaces packed[start..end) in place; per-node
// (deg, start) meta goes to global. The kernel boundary between sort and
// gather guarantees global visibility of everything the consumer reads.
// Buckets with m > SORT_CAP (>=16 sigma; effectively never) are left
// unsorted and flagged via bsort[b]=0; gather handles them by filter-scan.
// ---------------------------------------------------------------------------
__global__ void __launch_bounds__(512, 4)
sort_kernel(unsigned int* __restrict__ packed,
            const int* __restrict__ boffs,
            int* __restrict__ ndeg,
            int* __restrict__ nstart,
            int* __restrict__ bsort) {
    __shared__ unsigned int sorted[SORT_CAP];  // 20 KB
    __shared__ int hist[128];
    __shared__ int starts[128];
    __shared__ int curs[128];
    __shared__ int tmp[512];

    int b = blockIdx.x;
    int tid = threadIdx.x;
    int start = boffs[(long)b * EB];
    int end = (b + 1 < NBKT) ? boffs[(long)(b + 1) * EB] : N_EDGES;
    int m = end - start;

    if (tid < 128) hist[tid] = 0;
    __syncthreads();

    // 1. per-node histogram
    for (int k = tid; k < m; k += 512)
        atomicAdd(&hist[(int)(packed[start + k] >> 17)], 1);
    __syncthreads();

    // 2. exclusive scan (scan1's proven 512-wide pattern; entries >=128 = 0)
    int v = (tid < 128) ? hist[tid] : 0;
    tmp[tid] = v;
    __syncthreads();
#pragma unroll
    for (int d = 1; d < 512; d <<= 1) {
        int t = (tid >= d) ? tmp[tid - d] : 0;
        __syncthreads();
        tmp[tid] += t;
        __syncthreads();
    }
    if (tid < 128) {
        int s = tmp[tid] - v;
        starts[tid] = s;
        curs[tid] = s;
    }
    __syncthreads();

    bool fast = (m <= SORT_CAP);   // uniform across the block
    if (fast) {
        // 3. cursor-scatter src into sorted[]
        for (int k = tid; k < m; k += 512) {
            unsigned int w = packed[start + k];
            int l = (int)(w >> 17);
            int p = atomicAdd(&curs[l], 1);
            sorted[p] = w & 0x1FFFFu;
        }
        __threadfence_block();
        __syncthreads();
        // 4. write node-sorted src list back to global (dense, coalesced)
        for (int k = tid; k < m; k += 512)
            packed[start + k] = sorted[k];
    }

    // 5. per-node meta
    if (tid < 128) {
        int g = b * 128 + tid;
        if (g < N_NODES) {
            ndeg[g] = hist[tid];
            nstart[g] = start + starts[tid];
        }
    }
    if (tid == 0) bsort[b] = fast ? 1 : 0;
}

// ---------------------------------------------------------------------------
// Phase B2: barrier-free, LDS-free gather. 8 lanes per node, each lane owns
// 2 channels; serial unroll-2 over the node's contiguous src list; fused
// mean + bias + relu + W2-dot + b2; shfl-reduce; write out.
// 8-lane groups are g-uniform, so the early return never splits a group.
// ---------------------------------------------------------------------------
__global__ void __launch_bounds__(512, 8)
gather_kernel(const unsigned int* __restrict__ packed,
              const int* __restrict__ ndeg,
              const int* __restrict__ nstart,
              const int* __restrict__ bsort,
              const int* __restrict__ boffs,
              const __half2* __restrict__ h2,
              const float* __restrict__ b1,
              const float* __restrict__ W2,
              const float* __restrict__ b2,
              float* __restrict__ out) {
    int bb = blockIdx.x;                         // 2*NBKT blocks
    int b = bb >> 1;
    int l = (bb & 1) * 64 + (threadIdx.x >> 3);  // node-in-bucket 0..127
    int c = threadIdx.x & 7;                     // channel pair 0..7
    int g = b * 128 + l;
    if (g >= N_NODES) return;                    // group-uniform; no barriers

    int deg = ndeg[g];
    float2 acc0 = {0.0f, 0.0f}, acc1 = {0.0f, 0.0f};

    if (bsort[b]) {
        int p = nstart[g], pend = p + deg;
        for (; p + 1 < pend; p += 2) {
            int sA = (int)packed[p];
            int sB = (int)packed[p + 1];
            float2 fA = __half22float2(h2[(long)sA * 8 + c]);
            float2 fB = __half22float2(h2[(long)sB * 8 + c]);
            acc0.x += fA.x; acc0.y += fA.y;
            acc1.x += fB.x; acc1.y += fB.y;
        }
        if (p < pend) {
            float2 f = __half22float2(h2[(long)packed[p] * 8 + c]);
            acc0.x += f.x; acc0.y += f.y;
        }
    } else {
        // never-expected universal fallback: filter-scan the whole bucket
        int bs = boffs[(long)b * EB];
        int be = (b + 1 < NBKT) ? boffs[(long)(b + 1) * EB] : N_EDGES;
        for (int p = bs; p < be; ++p) {
            unsigned int w = packed[p];
            if ((int)(w >> 17) == l) {
                float2 f = __half22float2(h2[(long)(w & 0x1FFFFu) * 8 + c]);
                acc0.x += f.x; acc0.y += f.y;
            }
        }
    }

    float inv = 1.0f / fmaxf((float)deg, 1.0f);
    float sx = acc0.x + acc1.x, sy = acc0.y + acc1.y;
    float v = fmaxf(sx * inv + b1[2 * c], 0.0f)     * W2[2 * c]
            + fmaxf(sy * inv + b1[2 * c + 1], 0.0f) * W2[2 * c + 1];
    v += __shfl_xor(v, 1);
    v += __shfl_xor(v, 2);
    v += __shfl_xor(v, 4);
    if (c == 0) out[g] = v + b2[0];
}

// ---------------------------------------------------------------------------
// Fallback path (R0): atomic value scatter + finalize. Used if ws too small.
// ---------------------------------------------------------------------------
__global__ void linear1_f32_kernel(const float* __restrict__ x,
                                   const float* __restrict__ W1,
                                   float* __restrict__ h, int n) {
    __shared__ float w[16 * 58];
    for (int idx = threadIdx.x; idx < 16 * 58; idx += blockDim.x)
        w[idx] = W1[idx];
    __syncthreads();
    int i = blockIdx.x * blockDim.x + threadIdx.x;
    if (i >= n) return;
    float xv[58];
    const float* xr = x + (long)i * 58;
#pragma unroll
    for (int k = 0; k < 58; ++k) xv[k] = xr[k];
#pragma unroll
    for (int cq = 0; cq < 4; ++cq) {
        float a[4];
#pragma unroll
        for (int r = 0; r < 4; ++r) {
            int ch = cq * 4 + r;
            float acc = 0.0f;
#pragma unroll
            for (int k = 0; k < 58; ++k) acc += xv[k] * w[ch * 58 + k];
            a[r] = acc;
        }
        ((float4*)(h + (long)i * 16))[cq] = make_float4(a[0], a[1], a[2], a[3]);
    }
}

__global__ void scatter_kernel(const int* __restrict__ ei32,
                               const long long* __restrict__ ei64,
                               const unsigned int* __restrict__ flag,
                               const float* __restrict__ h,
                               float* __restrict__ summed,
                               float* __restrict__ cnt) {
    long e = (long)blockIdx.x * blockDim.x + threadIdx.x;
    if (e >= N_EDGES) return;
    long src, dst;
    if (*flag) { src = (long)ei64[e]; dst = (long)ei64[N_EDGES + e]; }
    else       { src = (long)ei32[e]; dst = (long)ei32[N_EDGES + e]; }
    const float4* hs = (const float4*)(h + src * 16);
    float4 a = hs[0], b = hs[1], c = hs[2], d = hs[3];
    float* o = summed + dst * 16;
    atomicAdd(o + 0,  a.x); atomicAdd(o + 1,  a.y);
    atomicAdd(o + 2,  a.z); atomicAdd(o + 3,  a.w);
    atomicAdd(o + 4,  b.x); atomicAdd(o + 5,  b.y);
    atomicAdd(o + 6,  b.z); atomicAdd(o + 7,  b.w);
    atomicAdd(o + 8,  c.x); atomicAdd(o + 9,  c.y);
    atomicAdd(o + 10, c.z); atomicAdd(o + 11, c.w);
    atomicAdd(o + 12, d.x); atomicAdd(o + 13, d.y);
    atomicAdd(o + 14, d.z); atomicAdd(o + 15, d.w);
    atomicAdd(cnt + dst, 1.0f);
}

__global__ void finalize_kernel(const float* __restrict__ summed,
                                const float* __restrict__ cnt,
                                const float* __restrict__ b1,
                                const float* __restrict__ W2,
                                const float* __restrict__ b2,
                                float* __restrict__ out, int n) {
    int i = blockIdx.x * blockDim.x + threadIdx.x;
    if (i >= n) return;
    const float4* s = (const float4*)(summed + (long)i * 16);
    float4 s0 = s[0], s1 = s[1], s2 = s[2], s3 = s[3];
    float sv[16] = {s0.x, s0.y, s0.z, s0.w, s1.x, s1.y, s1.z, s1.w,
                    s2.x, s2.y, s2.z, s2.w, s3.x, s3.y, s3.z, s3.w};
    float inv = 1.0f / fmaxf(cnt[i], 1.0f);
    float acc = b2[0];
#pragma unroll
    for (int c = 0; c < 16; ++c)
        acc += W2[c] * fmaxf(sv[c] * inv + b1[c], 0.0f);
    out[i] = acc;
}

extern "C" void kernel_launch(void* const* d_in, const int* in_sizes, int n_in,
                              void* d_out, int out_size, void* d_ws, size_t ws_size,
                              hipStream_t stream) {
    const float* x  = (const float*)d_in[0];
    const void*  ei = d_in[1];
    const float* W1 = (const float*)d_in[2];
    const float* b1 = (const float*)d_in[3];
    const float* W2 = (const float*)d_in[4];
    const float* b2 = (const float*)d_in[5];
    float* out = (float*)d_out;

    float* ws = (float*)d_ws;

    // Bucket-path workspace (4B words):
    //   h2     :   800,000  (fp16 h, __half2[N][8] = 3.2 MB)
    //   packed : 3,200,000  u32 (edge words; node-sorted in place by sort)
    //   bcount :   NSCAN    i32 (scanned in place -> offsets)
    //   bsums  :       512  i32
    //   flag   :         1  u32
    //   ndeg   :   100,000  i32
    //   nstart :   100,000  i32
    //   bsort  :       782  i32
    const size_t need_bkt =
        (size_t)(800000 + 3200000 + NSCAN + 512 + 1 + 100000 + 100000 + NBKT) * 4;

    if (ws_size >= need_bkt) {
        __half2*      h2     = (__half2*)ws;
        unsigned int* packed = (unsigned int*)(ws + 800000);
        int*          bcount = (int*)(ws + 800000 + 3200000);
        int*          bsums  = bcount + NSCAN;
        unsigned int* flag   = (unsigned int*)(bsums + 512);
        int*          ndeg   = (int*)(flag + 1);
        int*          nstart = ndeg + 100000;
        int*          bsort  = nstart + 100000;

        detect_i64_kernel<<<1, 64, 0, stream>>>((const unsigned int*)ei, flag);

        linear1_kernel<<<(N_NODES + 127) / 128, 128, 0, stream>>>(x, W1, h2, N_NODES);

        hist_kernel<<<EB, 512, 0, stream>>>(
            (const int*)ei, (const long long*)ei, flag, bcount);

        scan1_kernel<<<NB_SCAN, SCAN_BLOCK, 0, stream>>>(bcount, bsums, NSCAN);
        scan2_kernel<<<1, 512, 0, stream>>>(bsums, NB_SCAN);
        scan3_kernel<<<(NSCAN + 255) / 256, 256, 0, stream>>>(bcount, bsums, NSCAN);

        bucket_scatter_kernel<<<EB, 512, 0, stream>>>(
            (const int*)ei, (const long long*)ei, flag, bcount, packed);

        sort_kernel<<<NBKT, 512, 0, stream>>>(packed, bcount, ndeg, nstart, bsort);

        gather_kernel<<<NBKT * 2, 512, 0, stream>>>(
            packed, ndeg, nstart, bsort, bcount, h2, b1, W2, b2, out);
    } else {
        // Fallback: R0 atomic-scatter path (13.2 MB workspace).
        float* h      = ws;                  // N_NODES * 16
        float* summed = ws + N_NODES * 16;   // N_NODES * 16
        float* cnt    = ws + N_NODES * 32;   // N_NODES
        unsigned int* flag = (unsigned int*)(ws + N_NODES * 33);

        hipMemsetAsync(summed, 0, (size_t)(N_NODES * 17) * sizeof(float), stream);
        detect_i64_kernel<<<1, 64, 0, stream>>>((const unsigned int*)ei, flag);
        linear1_f32_kernel<<<(N_NODES + 127) / 128, 128, 0, stream>>>(x, W1, h, N_NODES);
        scatter_kernel<<<(N_EDGES + 255) / 256, 256, 0, stream>>>(
            (const int*)ei, (const long long*)ei, flag, h, summed, cnt);
        finalize_kernel<<<(N_NODES + 255) / 256, 256, 0, stream>>>(
            summed, cnt, b1, W2, b2, out, N_NODES);
    }
}

// Round 10
// 108.300 us; speedup vs baseline: 25.6839x; 1.0958x over previous
//
#include <hip/hip_runtime.h>
#include <hip/hip_fp16.h>

#define N_NODES 100000
#define N_EDGES 3200000
#define NBKT 782            // buckets of 128 nodes (dst >> 7)
#define EB 256              // phase-A blocks
#define EPB 12500           // edges per phase-A block (EB*EPB == N_EDGES)
#define SCAN_BLOCK 512
#define NSCAN (NBKT * EB)   // 200192 (bucket-major counts)
#define NB_SCAN ((NSCAN + SCAN_BLOCK - 1) / SCAN_BLOCK)  // 391 (<= 512)
#define SORT_CAP 5120       // per-bucket sorted-edge LDS capacity (20 KB)

// ---------------------------------------------------------------------------
// Detect int64 vs int32 edge_index (odd 32-bit words all zero => int64).
// ---------------------------------------------------------------------------
__global__ void detect_i64_kernel(const unsigned int* __restrict__ ei,
                                  unsigned int* __restrict__ flag) {
    unsigned int v = 0;
    int lane = threadIdx.x;  // 64 threads
    for (int j = lane; j < 512; j += 64) v |= ei[2 * j + 1];
    unsigned long long any_nonzero = __ballot(v != 0u);
    if (lane == 0) *flag = (any_nonzero == 0ULL) ? 1u : 0u;
}

// ---------------------------------------------------------------------------
// h2[i][c] = fp16( sum_k x[i][k] * W1[c][k] )  -- h stored as __half2[N][8]
// ---------------------------------------------------------------------------
__global__ void linear1_kernel(const float* __restrict__ x,
                               const float* __restrict__ W1,
                               __half2* __restrict__ h2, int n) {
    __shared__ float w[16 * 58];
    for (int idx = threadIdx.x; idx < 16 * 58; idx += blockDim.x)
        w[idx] = W1[idx];
    __syncthreads();

    int i = blockIdx.x * blockDim.x + threadIdx.x;
    if (i >= n) return;

    float xv[58];
    const float* xr = x + (long)i * 58;
#pragma unroll
    for (int k = 0; k < 58; ++k) xv[k] = xr[k];

    __half2 o[8];
#pragma unroll
    for (int q = 0; q < 8; ++q) {
        float a[2];
#pragma unroll
        for (int r = 0; r < 2; ++r) {
            int c = q * 2 + r;
            float acc = 0.0f;
#pragma unroll
            for (int k = 0; k < 58; ++k) acc += xv[k] * w[c * 58 + k];
            a[r] = acc;
        }
        o[q] = __floats2half2_rn(a[0], a[1]);
    }
    float4* dst = (float4*)(h2 + (long)i * 8);
    float4* src = (float4*)o;
    dst[0] = src[0];
    dst[1] = src[1];
}

// ---------------------------------------------------------------------------
// Phase A1: per-(bucket, block) histogram of dst buckets.
// ---------------------------------------------------------------------------
__global__ void hist_kernel(const int* __restrict__ ei32,
                            const long long* __restrict__ ei64,
                            const unsigned int* __restrict__ flag,
                            int* __restrict__ bcount) {
    __shared__ int hist[NBKT];
    for (int i = threadIdx.x; i < NBKT; i += blockDim.x) hist[i] = 0;
    __syncthreads();

    long base = (long)blockIdx.x * EPB;
    bool i64 = (*flag != 0u);
    for (int k = threadIdx.x; k < EPB; k += blockDim.x) {
        long e = base + k;
        int dst = i64 ? (int)ei64[N_EDGES + e] : ei32[N_EDGES + e];
        atomicAdd(&hist[dst >> 7], 1);
    }
    __syncthreads();
    for (int b = threadIdx.x; b < NBKT; b += blockDim.x)
        bcount[(long)b * EB + blockIdx.x] = hist[b];
}

// ---------------------------------------------------------------------------
// In-place exclusive scan of bcount (NSCAN entries), 3 kernels.
// ---------------------------------------------------------------------------
__global__ void scan1_kernel(int* __restrict__ data,
                             int* __restrict__ bsums, int n) {
    __shared__ int tmp[SCAN_BLOCK];
    int i = blockIdx.x * SCAN_BLOCK + threadIdx.x;
    int v = (i < n) ? data[i] : 0;
    tmp[threadIdx.x] = v;
    __syncthreads();
#pragma unroll
    for (int d = 1; d < SCAN_BLOCK; d <<= 1) {
        int t = (threadIdx.x >= d) ? tmp[threadIdx.x - d] : 0;
        __syncthreads();
        tmp[threadIdx.x] += t;
        __syncthreads();
    }
    if (i < n) data[i] = tmp[threadIdx.x] - v;  // exclusive
    if (threadIdx.x == SCAN_BLOCK - 1) bsums[blockIdx.x] = tmp[threadIdx.x];
}

__global__ void scan2_kernel(int* __restrict__ bsums, int nb) {
    __shared__ int tmp[512];
    int i = threadIdx.x;
    int v = (i < nb) ? bsums[i] : 0;
    tmp[i] = v;
    __syncthreads();
#pragma unroll
    for (int d = 1; d < 512; d <<= 1) {
        int t = (i >= d) ? tmp[i - d] : 0;
        __syncthreads();
        tmp[i] += t;
        __syncthreads();
    }
    if (i < nb) bsums[i] = tmp[i] - v;  // exclusive
}

__global__ void scan3_kernel(int* __restrict__ data,
                             const int* __restrict__ bsums, int n) {
    int i = blockIdx.x * blockDim.x + threadIdx.x;
    if (i < n) data[i] += bsums[i / SCAN_BLOCK];
}

// ---------------------------------------------------------------------------
// Phase A2 (redesigned): LDS-sorted scatter. Each block counting-sorts its
// 12500 edges by dst-bucket in LDS, then streams them to global in
// bucket-grouped order: consecutive LDS slots map to consecutive global
// addresses within each (bucket, block) run (~64B dense chunks), so a
// wave's 64 stores touch ~4 cache lines instead of ~60.
// Output content is identical to the old per-edge scatter (order within a
// bucket differs, which the downstream node-sort doesn't care about).
// ---------------------------------------------------------------------------
__global__ void __launch_bounds__(1024, 1)
scatter_sort_kernel(const int* __restrict__ ei32,
                    const long long* __restrict__ ei64,
                    const unsigned int* __restrict__ flag,
                    const int* __restrict__ boffs,
                    unsigned int* __restrict__ packed) {
    __shared__ unsigned int vals[EPB];        // 50.0 KB  bucket-grouped words
    __shared__ unsigned short bjs[EPB];       // 25.0 KB  bucket id per slot
    __shared__ int hist[NBKT];
    __shared__ int curs[NBKT];
    __shared__ int gbase[NBKT];
    __shared__ int tmp[1024];

    int tid = threadIdx.x;
    long base = (long)blockIdx.x * EPB;
    bool i64 = (*flag != 0u);

    for (int i = tid; i < NBKT; i += 1024) hist[i] = 0;
    __syncthreads();

    // pass 1: per-bucket histogram
    for (int k = tid; k < EPB; k += 1024) {
        long e = base + k;
        int dst = i64 ? (int)ei64[N_EDGES + e] : ei32[N_EDGES + e];
        atomicAdd(&hist[dst >> 7], 1);
    }
    __syncthreads();

    // 1024-wide exclusive scan (entries >= NBKT padded 0)
    int v = (tid < NBKT) ? hist[tid] : 0;
    tmp[tid] = v;
    __syncthreads();
#pragma unroll
    for (int d = 1; d < 1024; d <<= 1) {
        int t = (tid >= d) ? tmp[tid - d] : 0;
        __syncthreads();
        tmp[tid] += t;
        __syncthreads();
    }
    if (tid < NBKT) {
        int s = tmp[tid] - v;                           // local start
        curs[tid] = s;
        gbase[tid] = boffs[(long)tid * EB + blockIdx.x] - s;
    }
    __syncthreads();

    // pass 2: cursor-scatter into LDS (bucket-grouped), re-read edges (L2-hot)
    for (int k = tid; k < EPB; k += 1024) {
        long e = base + k;
        int src, dst;
        if (i64) { src = (int)ei64[e]; dst = (int)ei64[N_EDGES + e]; }
        else     { src = ei32[e];      dst = ei32[N_EDGES + e]; }
        int b = dst >> 7;
        int p = atomicAdd(&curs[b], 1);
        vals[p] = ((unsigned int)(dst & 127) << 17) | (unsigned int)src;
        bjs[p] = (unsigned short)b;
    }
    __threadfence_block();
    __syncthreads();

    // pass 3: dense-chunk copy to global (consecutive j -> consecutive dest
    // within each bucket run)
    for (int j = tid; j < EPB; j += 1024)
        packed[gbase[bjs[j]] + j] = vals[j];
}

// ---------------------------------------------------------------------------
// Phase B1: per-bucket counting sort in LDS, written BACK TO GLOBAL.
// ---------------------------------------------------------------------------
__global__ void __launch_bounds__(512, 4)
sort_kernel(unsigned int* __restrict__ packed,
            const int* __restrict__ boffs,
            int* __restrict__ ndeg,
            int* __restrict__ nstart,
            int* __restrict__ bsort) {
    __shared__ unsigned int sorted[SORT_CAP];  // 20 KB
    __shared__ int hist[128];
    __shared__ int starts[128];
    __shared__ int curs[128];
    __shared__ int tmp[512];

    int b = blockIdx.x;
    int tid = threadIdx.x;
    int start = boffs[(long)b * EB];
    int end = (b + 1 < NBKT) ? boffs[(long)(b + 1) * EB] : N_EDGES;
    int m = end - start;

    if (tid < 128) hist[tid] = 0;
    __syncthreads();

    // 1. per-node histogram
    for (int k = tid; k < m; k += 512)
        atomicAdd(&hist[(int)(packed[start + k] >> 17)], 1);
    __syncthreads();

    // 2. exclusive scan
    int v = (tid < 128) ? hist[tid] : 0;
    tmp[tid] = v;
    __syncthreads();
#pragma unroll
    for (int d = 1; d < 512; d <<= 1) {
        int t = (tid >= d) ? tmp[tid - d] : 0;
        __syncthreads();
        tmp[tid] += t;
        __syncthreads();
    }
    if (tid < 128) {
        int s = tmp[tid] - v;
        starts[tid] = s;
        curs[tid] = s;
    }
    __syncthreads();

    bool fast = (m <= SORT_CAP);   // uniform across the block
    if (fast) {
        // 3. cursor-scatter src into sorted[]
        for (int k = tid; k < m; k += 512) {
            unsigned int w = packed[start + k];
            int l = (int)(w >> 17);
            int p = atomicAdd(&curs[l], 1);
            sorted[p] = w & 0x1FFFFu;
        }
        __threadfence_block();
        __syncthreads();
        // 4. write node-sorted src list back to global (dense, coalesced)
        for (int k = tid; k < m; k += 512)
            packed[start + k] = sorted[k];
    }

    // 5. per-node meta
    if (tid < 128) {
        int g = b * 128 + tid;
        if (g < N_NODES) {
            ndeg[g] = hist[tid];
            nstart[g] = start + starts[tid];
        }
    }
    if (tid == 0) bsort[b] = fast ? 1 : 0;
}

// ---------------------------------------------------------------------------
// Phase B2: barrier-free, LDS-free gather. 8 lanes per node, each lane owns
// 2 channels; fused mean + bias + relu + W2-dot + b2; shfl-reduce.
// ---------------------------------------------------------------------------
__global__ void __launch_bounds__(512, 8)
gather_kernel(const unsigned int* __restrict__ packed,
              const int* __restrict__ ndeg,
              const int* __restrict__ nstart,
              const int* __restrict__ bsort,
              const int* __restrict__ boffs,
              const __half2* __restrict__ h2,
              const float* __restrict__ b1,
              const float* __restrict__ W2,
              const float* __restrict__ b2,
              float* __restrict__ out) {
    int bb = blockIdx.x;                         // 2*NBKT blocks
    int b = bb >> 1;
    int l = (bb & 1) * 64 + (threadIdx.x >> 3);  // node-in-bucket 0..127
    int c = threadIdx.x & 7;                     // channel pair 0..7
    int g = b * 128 + l;
    if (g >= N_NODES) return;                    // group-uniform; no barriers

    int deg = ndeg[g];
    float2 acc0 = {0.0f, 0.0f}, acc1 = {0.0f, 0.0f};

    if (bsort[b]) {
        int p = nstart[g], pend = p + deg;
        for (; p + 1 < pend; p += 2) {
            int sA = (int)packed[p];
            int sB = (int)packed[p + 1];
            float2 fA = __half22float2(h2[(long)sA * 8 + c]);
            float2 fB = __half22float2(h2[(long)sB * 8 + c]);
            acc0.x += fA.x; acc0.y += fA.y;
            acc1.x += fB.x; acc1.y += fB.y;
        }
        if (p < pend) {
            float2 f = __half22float2(h2[(long)packed[p] * 8 + c]);
            acc0.x += f.x; acc0.y += f.y;
        }
    } else {
        // never-expected universal fallback: filter-scan the whole bucket
        int bs = boffs[(long)b * EB];
        int be = (b + 1 < NBKT) ? boffs[(long)(b + 1) * EB] : N_EDGES;
        for (int p = bs; p < be; ++p) {
            unsigned int w = packed[p];
            if ((int)(w >> 17) == l) {
                float2 f = __half22float2(h2[(long)(w & 0x1FFFFu) * 8 + c]);
                acc0.x += f.x; acc0.y += f.y;
            }
        }
    }

    float inv = 1.0f / fmaxf((float)deg, 1.0f);
    float sx = acc0.x + acc1.x, sy = acc0.y + acc1.y;
    float v = fmaxf(sx * inv + b1[2 * c], 0.0f)     * W2[2 * c]
            + fmaxf(sy * inv + b1[2 * c + 1], 0.0f) * W2[2 * c + 1];
    v += __shfl_xor(v, 1);
    v += __shfl_xor(v, 2);
    v += __shfl_xor(v, 4);
    if (c == 0) out[g] = v + b2[0];
}

// ---------------------------------------------------------------------------
// Fallback path (R0): atomic value scatter + finalize. Used if ws too small.
// ---------------------------------------------------------------------------
__global__ void linear1_f32_kernel(const float* __restrict__ x,
                                   const float* __restrict__ W1,
                                   float* __restrict__ h, int n) {
    __shared__ float w[16 * 58];
    for (int idx = threadIdx.x; idx < 16 * 58; idx += blockDim.x)
        w[idx] = W1[idx];
    __syncthreads();
    int i = blockIdx.x * blockDim.x + threadIdx.x;
    if (i >= n) return;
    float xv[58];
    const float* xr = x + (long)i * 58;
#pragma unroll
    for (int k = 0; k < 58; ++k) xv[k] = xr[k];
#pragma unroll
    for (int cq = 0; cq < 4; ++cq) {
        float a[4];
#pragma unroll
        for (int r = 0; r < 4; ++r) {
            int ch = cq * 4 + r;
            float acc = 0.0f;
#pragma unroll
            for (int k = 0; k < 58; ++k) acc += xv[k] * w[ch * 58 + k];
            a[r] = acc;
        }
        ((float4*)(h + (long)i * 16))[cq] = make_float4(a[0], a[1], a[2], a[3]);
    }
}

__global__ void scatter_kernel(const int* __restrict__ ei32,
                               const long long* __restrict__ ei64,
                               const unsigned int* __restrict__ flag,
                               const float* __restrict__ h,
                               float* __restrict__ summed,
                               float* __restrict__ cnt) {
    long e = (long)blockIdx.x * blockDim.x + threadIdx.x;
    if (e >= N_EDGES) return;
    long src, dst;
    if (*flag) { src = (long)ei64[e]; dst = (long)ei64[N_EDGES + e]; }
    else       { src = (long)ei32[e]; dst = (long)ei32[N_EDGES + e]; }
    const float4* hs = (const float4*)(h + src * 16);
    float4 a = hs[0], b = hs[1], c = hs[2], d = hs[3];
    float* o = summed + dst * 16;
    atomicAdd(o + 0,  a.x); atomicAdd(o + 1,  a.y);
    atomicAdd(o + 2,  a.z); atomicAdd(o + 3,  a.w);
    atomicAdd(o + 4,  b.x); atomicAdd(o + 5,  b.y);
    atomicAdd(o + 6,  b.z); atomicAdd(o + 7,  b.w);
    atomicAdd(o + 8,  c.x); atomicAdd(o + 9,  c.y);
    atomicAdd(o + 10, c.z); atomicAdd(o + 11, c.w);
    atomicAdd(o + 12, d.x); atomicAdd(o + 13, d.y);
    atomicAdd(o + 14, d.z); atomicAdd(o + 15, d.w);
    atomicAdd(cnt + dst, 1.0f);
}

__global__ void finalize_kernel(const float* __restrict__ summed,
                                const float* __restrict__ cnt,
                                const float* __restrict__ b1,
                                const float* __restrict__ W2,
                                const float* __restrict__ b2,
                                float* __restrict__ out, int n) {
    int i = blockIdx.x * blockDim.x + threadIdx.x;
    if (i >= n) return;
    const float4* s = (const float4*)(summed + (long)i * 16);
    float4 s0 = s[0], s1 = s[1], s2 = s[2], s3 = s[3];
    float sv[16] = {s0.x, s0.y, s0.z, s0.w, s1.x, s1.y, s1.z, s1.w,
                    s2.x, s2.y, s2.z, s2.w, s3.x, s3.y, s3.z, s3.w};
    float inv = 1.0f / fmaxf(cnt[i], 1.0f);
    float acc = b2[0];
#pragma unroll
    for (int c = 0; c < 16; ++c)
        acc += W2[c] * fmaxf(sv[c] * inv + b1[c], 0.0f);
    out[i] = acc;
}

extern "C" void kernel_launch(void* const* d_in, const int* in_sizes, int n_in,
                              void* d_out, int out_size, void* d_ws, size_t ws_size,
                              hipStream_t stream) {
    const float* x  = (const float*)d_in[0];
    const void*  ei = d_in[1];
    const float* W1 = (const float*)d_in[2];
    const float* b1 = (const float*)d_in[3];
    const float* W2 = (const float*)d_in[4];
    const float* b2 = (const float*)d_in[5];
    float* out = (float*)d_out;

    float* ws = (float*)d_ws;

    // Bucket-path workspace (4B words):
    //   h2     :   800,000  (fp16 h, __half2[N][8] = 3.2 MB)
    //   packed : 3,200,000  u32 (edge words; node-sorted in place by sort)
    //   bcount :   NSCAN    i32 (scanned in place -> offsets)
    //   bsums  :       512  i32
    //   flag   :         1  u32
    //   ndeg   :   100,000  i32
    //   nstart :   100,000  i32
    //   bsort  :       782  i32
    const size_t need_bkt =
        (size_t)(800000 + 3200000 + NSCAN + 512 + 1 + 100000 + 100000 + NBKT) * 4;

    if (ws_size >= need_bkt) {
        __half2*      h2     = (__half2*)ws;
        unsigned int* packed = (unsigned int*)(ws + 800000);
        int*          bcount = (int*)(ws + 800000 + 3200000);
        int*          bsums  = bcount + NSCAN;
        unsigned int* flag   = (unsigned int*)(bsums + 512);
        int*          ndeg   = (int*)(flag + 1);
        int*          nstart = ndeg + 100000;
        int*          bsort  = nstart + 100000;

        detect_i64_kernel<<<1, 64, 0, stream>>>((const unsigned int*)ei, flag);

        linear1_kernel<<<(N_NODES + 127) / 128, 128, 0, stream>>>(x, W1, h2, N_NODES);

        hist_kernel<<<EB, 512, 0, stream>>>(
            (const int*)ei, (const long long*)ei, flag, bcount);

        scan1_kernel<<<NB_SCAN, SCAN_BLOCK, 0, stream>>>(bcount, bsums, NSCAN);
        scan2_kernel<<<1, 512, 0, stream>>>(bsums, NB_SCAN);
        scan3_kernel<<<(NSCAN + 255) / 256, 256, 0, stream>>>(bcount, bsums, NSCAN);

        scatter_sort_kernel<<<EB, 1024, 0, stream>>>(
            (const int*)ei, (const long long*)ei, flag, bcount, packed);

        sort_kernel<<<NBKT, 512, 0, stream>>>(packed, bcount, ndeg, nstart, bsort);

        gather_kernel<<<NBKT * 2, 512, 0, stream>>>(
            packed, ndeg, nstart, bsort, bcount, h2, b1, W2, b2, out);
    } else {
        // Fallback: R0 atomic-scatter path (13.2 MB workspace).
        float* h      = ws;                  // N_NODES * 16
        float* summed = ws + N_NODES * 16;   // N_NODES * 16
        float* cnt    = ws + N_NODES * 32;   // N_NODES
        unsigned int* flag = (unsigned int*)(ws + N_NODES * 33);

        hipMemsetAsync(summed, 0, (size_t)(N_NODES * 17) * sizeof(float), stream);
        detect_i64_kernel<<<1, 64, 0, stream>>>((const unsigned int*)ei, flag);
        linear1_f32_kernel<<<(N_NODES + 127) / 128, 128, 0, stream>>>(x, W1, h, N_NODES);
        scatter_kernel<<<(N_EDGES + 255) / 256, 256, 0, stream>>>(
            (const int*)ei, (const long long*)ei, flag, h, summed, cnt);
        finalize_kernel<<<(N_NODES + 255) / 256, 256, 0, stream>>>(
            summed, cnt, b1, W2, b2, out, N_NODES);
    }
}